// Round 1
// baseline (630.650 us; speedup 1.0000x reference)
//
#include <hip/hip_runtime.h>
#include <math.h>

// Problem constants
#define SEQ 4096          // N*N tokens
#define DIM 34
#define NHEAD 2
#define HD 17
#define FFDIM 2048
#define QKV_LD 102        // 3*DIM
#define ATT_SCALE 0.2425356250363330f  // 1/sqrt(17)

// ---------------------------------------------------------------------------
// Kernel 1: conv1 -> relu -> conv2 -> relu -> cell[64][16]; agent_idx; a_emb
// ---------------------------------------------------------------------------
__global__ __launch_bounds__(256) void wm_prep(
    const float* __restrict__ obs, const int* __restrict__ action,
    const float* __restrict__ c1w, const float* __restrict__ c1b,
    const float* __restrict__ c2w, const float* __restrict__ c2b,
    const float* __restrict__ aw,  const float* __restrict__ ab,
    float* __restrict__ cell, float* __restrict__ aemb, int* __restrict__ agent_idx)
{
    __shared__ float h1[16][64];
    const int tid = threadIdx.x;
    // conv1: [2,8,8] -> [16,8,8]
    for (int e = tid; e < 1024; e += 256) {
        int o = e >> 6, y = (e >> 3) & 7, xx = e & 7;
        float a = c1b[o];
        for (int i = 0; i < 2; ++i)
            for (int ky = 0; ky < 3; ++ky) {
                int iy = y + ky - 1;
                if (iy < 0 || iy > 7) continue;
                for (int kx = 0; kx < 3; ++kx) {
                    int ix = xx + kx - 1;
                    if (ix < 0 || ix > 7) continue;
                    a += obs[i*64 + iy*8 + ix] * c1w[((o*2 + i)*3 + ky)*3 + kx];
                }
            }
        h1[o][y*8 + xx] = fmaxf(a, 0.f);
    }
    __syncthreads();
    // conv2: [16,8,8] -> [16,8,8]; cell[n][c] = out[c][n]
    for (int e = tid; e < 1024; e += 256) {
        int o = e >> 6, n = e & 63, y = n >> 3, xx = n & 7;
        float a = c2b[o];
        for (int i = 0; i < 16; ++i)
            for (int ky = 0; ky < 3; ++ky) {
                int iy = y + ky - 1;
                if (iy < 0 || iy > 7) continue;
                for (int kx = 0; kx < 3; ++kx) {
                    int ix = xx + kx - 1;
                    if (ix < 0 || ix > 7) continue;
                    a += h1[i][iy*8 + ix] * c2w[((o*16 + i)*3 + ky)*3 + kx];
                }
            }
        cell[n*16 + o] = fmaxf(a, 0.f);
    }
    // agent_idx = argmax(obs[0]) (first occurrence)
    if (tid < 64) {
        float v = obs[tid];
        float mx = v;
        for (int off = 32; off; off >>= 1) mx = fmaxf(mx, __shfl_xor(mx, off));
        unsigned long long mask = __ballot(v == mx);
        if (tid == 0) *agent_idx = (int)(__ffsll(mask) - 1);
    }
    // a_emb = relu(one_hot(action) @ act_w.T + act_b)
    if (tid >= 64 && tid < 72) {
        int k = tid - 64;
        int act = *action;
        aemb[k] = fmaxf(aw[k*4 + act] + ab[k], 0.f);
    }
}

// ---------------------------------------------------------------------------
// Kernel 2: build seq [4096][34]: [cell_i(16), cell_j(16), dx, dy]
// ---------------------------------------------------------------------------
__global__ __launch_bounds__(256) void wm_seq(const float* __restrict__ cell,
                                              float* __restrict__ x)
{
    __shared__ float cs[64][16];
    const int tid = threadIdx.x;
    for (int e = tid; e < 1024; e += 256) cs[e >> 4][e & 15] = cell[e];
    __syncthreads();
    const int t0 = blockIdx.x * 256;
    for (int e = tid; e < 256 * DIM; e += 256) {
        int t = t0 + e / DIM, d = e % DIM;
        int i = t >> 6, j = t & 63;
        float v;
        if (d < 16)       v = cs[i][d];
        else if (d < 32)  v = cs[j][d - 16];
        else if (d == 32) v = (float)((i >> 3) - (j >> 3)) * (1.0f / 3.5f);
        else              v = (float)((i & 7) - (j & 7)) * (1.0f / 3.5f);
        x[t0 * DIM + e] = v;
    }
}

// ---------------------------------------------------------------------------
// Kernel 3: qkv = x @ in_w.T + in_b   [4096][102]
// ---------------------------------------------------------------------------
__global__ __launch_bounds__(256) void wm_qkv(const float* __restrict__ x,
                                              const float* __restrict__ w,
                                              const float* __restrict__ b,
                                              float* __restrict__ out)
{
    int e = blockIdx.x * 256 + threadIdx.x;       // e < 4096*102 exactly
    int t = e / QKV_LD, k = e % QKV_LD;
    const float* xr = x + t * DIM;
    const float* wr = w + k * DIM;
    float acc = b[k];
    #pragma unroll
    for (int d = 0; d < DIM; ++d) acc = fmaf(xr[d], wr[d], acc);
    out[e] = acc;
}

// ---------------------------------------------------------------------------
// Kernel 4: flash attention. block: 16 queries x 16 key-groups (256 thr).
// grid: (256 q-tiles, 2 heads). Key tile staged in LDS = 128 keys.
// ---------------------------------------------------------------------------
__global__ __launch_bounds__(256) void wm_attn(const float* __restrict__ qkv,
                                               float* __restrict__ o)
{
    const int qt  = blockIdx.x;       // 0..255
    const int h   = blockIdx.y;       // 0..1
    const int tid = threadIdx.x;
    const int q   = tid & 15;         // local query
    const int g   = tid >> 4;         // key group 0..15

    __shared__ float Qs[16][HD];
    __shared__ float Ks[128][HD];
    __shared__ float Vs[128][HD];
    __shared__ float Pm[16][16];      // [group][query]
    __shared__ float Ps[16][16];
    __shared__ float Pa[16][16][HD];
    __shared__ float Pw[16][16];

    for (int e = tid; e < 16 * HD; e += 256) {
        int r = e / HD, d = e % HD;
        Qs[r][d] = qkv[(qt*16 + r)*QKV_LD + h*HD + d];
    }
    __syncthreads();
    float qr[HD];
    #pragma unroll
    for (int d = 0; d < HD; ++d) qr[d] = Qs[q][d];

    float m = -INFINITY, s = 0.f, acc[HD];
    #pragma unroll
    for (int d = 0; d < HD; ++d) acc[d] = 0.f;

    for (int kt = 0; kt < SEQ / 128; ++kt) {
        __syncthreads();
        for (int e = tid; e < 128 * HD; e += 256) {
            int r = e / HD, d = e % HD;
            int base = (kt*128 + r)*QKV_LD + h*HD + d;
            Ks[r][d] = qkv[base + DIM];
            Vs[r][d] = qkv[base + 2*DIM];
        }
        __syncthreads();
        for (int kk = 0; kk < 8; ++kk) {
            int kl = g*8 + kk;
            float sc = 0.f;
            #pragma unroll
            for (int d = 0; d < HD; ++d) sc = fmaf(qr[d], Ks[kl][d], sc);
            sc *= ATT_SCALE;
            if (sc > m) {
                float corr = __expf(m - sc);
                s = s * corr + 1.0f;
                #pragma unroll
                for (int d = 0; d < HD; ++d) acc[d] = fmaf(acc[d], corr, Vs[kl][d]);
                m = sc;
            } else {
                float p = __expf(sc - m);
                s += p;
                #pragma unroll
                for (int d = 0; d < HD; ++d) acc[d] = fmaf(p, Vs[kl][d], acc[d]);
            }
        }
    }
    Pm[g][q] = m; Ps[g][q] = s;
    #pragma unroll
    for (int d = 0; d < HD; ++d) Pa[g][q][d] = acc[d];
    __syncthreads();
    if (tid < 16) {
        float M = Pm[0][tid];
        for (int gg = 1; gg < 16; ++gg) M = fmaxf(M, Pm[gg][tid]);
        float S = 0.f;
        float w[16];
        for (int gg = 0; gg < 16; ++gg) { w[gg] = __expf(Pm[gg][tid] - M); S += Ps[gg][tid] * w[gg]; }
        float inv = 1.0f / S;
        for (int gg = 0; gg < 16; ++gg) Pw[gg][tid] = w[gg] * inv;
    }
    __syncthreads();
    for (int e = tid; e < 16 * HD; e += 256) {
        int qq = e / HD, d = e % HD;
        float out = 0.f;
        for (int gg = 0; gg < 16; ++gg) out = fmaf(Pa[gg][qq][d], Pw[gg][qq], out);
        o[(qt*16 + qq)*DIM + h*HD + d] = out;
    }
}

// ---------------------------------------------------------------------------
// Kernel 5: x = LN(x + o @ out_w.T + out_b). One wave per token.
// ---------------------------------------------------------------------------
__global__ __launch_bounds__(256) void wm_projln(float* __restrict__ x,
                                                 const float* __restrict__ o,
                                                 const float* __restrict__ w,
                                                 const float* __restrict__ b,
                                                 const float* __restrict__ g,
                                                 const float* __restrict__ be)
{
    const int wv = threadIdx.x >> 6, lane = threadIdx.x & 63;
    const int t = blockIdx.x * 4 + wv;
    const float* orow = o + t * DIM;
    float r = 0.f;
    if (lane < DIM) {
        float accv = b[lane];
        const float* wr = w + lane * DIM;
        #pragma unroll
        for (int e = 0; e < DIM; ++e) accv = fmaf(orow[e], wr[e], accv);
        r = x[t*DIM + lane] + accv;
    }
    float s1 = r, s2 = r * r;
    for (int off = 32; off; off >>= 1) { s1 += __shfl_xor(s1, off); s2 += __shfl_xor(s2, off); }
    float mean = s1 * (1.0f / DIM);
    float var  = s2 * (1.0f / DIM) - mean * mean;
    float rstd = rsqrtf(var + 1e-5f);
    if (lane < DIM) x[t*DIM + lane] = (r - mean) * rstd * g[lane] + be[lane];
}

// ---------------------------------------------------------------------------
// Kernel 6: fused FFN + residual + LN2, in-place on x.
// Block handles 16 tokens; hidden computed in 8 chunks of 256 staged in LDS.
// ---------------------------------------------------------------------------
__global__ __launch_bounds__(256) void wm_ff(float* __restrict__ x,
                                             const float* __restrict__ w1,
                                             const float* __restrict__ b1,
                                             const float* __restrict__ w2,
                                             const float* __restrict__ b2,
                                             const float* __restrict__ g,
                                             const float* __restrict__ be)
{
    __shared__ float xs[16][DIM];
    __shared__ float hs[16][256];
    __shared__ float ys[16][DIM];
    __shared__ float stats[16][2];
    const int tid = threadIdx.x;
    const int t0 = blockIdx.x * 16;

    for (int e = tid; e < 16 * DIM; e += 256) xs[e / DIM][e % DIM] = x[t0*DIM + e];

    // output slots: s0 = tid (covers (d, token-pair)), s1 = tid+256 for tid<16
    const int d0  = tid % DIM, tp0 = tid / DIM;          // slot0: tokens 2*tp0, 2*tp0+1
    const int s1v = tid + 256;
    const int d1  = s1v % DIM, tp1 = s1v / DIM;
    const bool has1 = (s1v < 272);
    float y00 = 0.f, y01 = 0.f, y10 = 0.f, y11 = 0.f;
    __syncthreads();

    for (int ch = 0; ch < FFDIM / 256; ++ch) {
        // phase 1: h[t][f] for f = ch*256 + tid, all 16 tokens
        const int f = ch * 256 + tid;
        const float* wr = w1 + f * DIM;
        float wreg[DIM];
        #pragma unroll
        for (int d = 0; d < DIM; ++d) wreg[d] = wr[d];
        const float bb = b1[f];
        if (ch) __syncthreads();           // phase2 of prev chunk done reading hs
        for (int t = 0; t < 16; ++t) {
            float a = bb;
            #pragma unroll
            for (int d = 0; d < DIM; ++d) a = fmaf(xs[t][d], wreg[d], a);
            hs[t][tid] = fmaxf(a, 0.f);
        }
        __syncthreads();
        // phase 2: accumulate y[t][d] over this chunk's 256 hidden units
        {
            const float4* wv = (const float4*)(w2 + d0*FFDIM + ch*256);
            const float4* h0 = (const float4*)hs[tp0*2];
            const float4* h1 = (const float4*)hs[tp0*2 + 1];
            for (int f4 = 0; f4 < 64; ++f4) {
                float4 ww = wv[f4];
                float4 a = h0[f4], b4 = h1[f4];
                y00 += a.x*ww.x + a.y*ww.y + a.z*ww.z + a.w*ww.w;
                y01 += b4.x*ww.x + b4.y*ww.y + b4.z*ww.z + b4.w*ww.w;
            }
        }
        if (has1) {
            const float4* wv = (const float4*)(w2 + d1*FFDIM + ch*256);
            const float4* h0 = (const float4*)hs[tp1*2];
            const float4* h1 = (const float4*)hs[tp1*2 + 1];
            for (int f4 = 0; f4 < 64; ++f4) {
                float4 ww = wv[f4];
                float4 a = h0[f4], b4 = h1[f4];
                y10 += a.x*ww.x + a.y*ww.y + a.z*ww.z + a.w*ww.w;
                y11 += b4.x*ww.x + b4.y*ww.y + b4.z*ww.z + b4.w*ww.w;
            }
        }
    }
    __syncthreads();
    // residual + bias into ys
    ys[tp0*2][d0]     = xs[tp0*2][d0]     + y00 + b2[d0];
    ys[tp0*2 + 1][d0] = xs[tp0*2 + 1][d0] + y01 + b2[d0];
    if (has1) {
        ys[tp1*2][d1]     = xs[tp1*2][d1]     + y10 + b2[d1];
        ys[tp1*2 + 1][d1] = xs[tp1*2 + 1][d1] + y11 + b2[d1];
    }
    __syncthreads();
    if (tid < 16) {
        float s1 = 0.f, s2 = 0.f;
        #pragma unroll
        for (int d = 0; d < DIM; ++d) { float v = ys[tid][d]; s1 += v; s2 += v * v; }
        float mean = s1 * (1.0f / DIM);
        float var  = s2 * (1.0f / DIM) - mean * mean;
        stats[tid][0] = mean;
        stats[tid][1] = rsqrtf(var + 1e-5f);
    }
    __syncthreads();
    for (int e = tid; e < 16 * DIM; e += 256) {
        int t = e / DIM, d = e % DIM;
        x[t0*DIM + e] = (ys[t][d] - stats[t][0]) * stats[t][1] * g[d] + be[d];
    }
}

// ---------------------------------------------------------------------------
// Kernel 7: hvec = mean of agent rows; out = [hvec, a_emb] @ head_w.T + head_b
// ---------------------------------------------------------------------------
__global__ __launch_bounds__(64) void wm_final(const float* __restrict__ x,
                                               const int* __restrict__ agent_idx,
                                               const float* __restrict__ aemb,
                                               const float* __restrict__ hw,
                                               const float* __restrict__ hb,
                                               float* __restrict__ out)
{
    __shared__ float hv[DIM];
    const int tid = threadIdx.x;
    const int ai = *agent_idx;
    if (tid < DIM) {
        float s = 0.f;
        for (int r = 0; r < 64; ++r) s += x[(ai*64 + r)*DIM + tid];
        hv[tid] = s * (1.0f / 64.0f);
    }
    __syncthreads();
    if (tid < 16) {
        float a = hb[tid];
        #pragma unroll
        for (int d = 0; d < DIM; ++d) a = fmaf(hv[d], hw[tid*42 + d], a);
        #pragma unroll
        for (int j = 0; j < 8; ++j) a = fmaf(aemb[j], hw[tid*42 + DIM + j], a);
        out[tid] = a;
    }
}

// ---------------------------------------------------------------------------
extern "C" void kernel_launch(void* const* d_in, const int* in_sizes, int n_in,
                              void* d_out, int out_size, void* d_ws, size_t ws_size,
                              hipStream_t stream)
{
    const float* obs    = (const float*)d_in[0];
    const int*   action = (const int*)  d_in[1];
    const float* c1w = (const float*)d_in[2];
    const float* c1b = (const float*)d_in[3];
    const float* c2w = (const float*)d_in[4];
    const float* c2b = (const float*)d_in[5];
    const float* aw  = (const float*)d_in[30];
    const float* ab  = (const float*)d_in[31];
    const float* hw  = (const float*)d_in[32];
    const float* hb  = (const float*)d_in[33];

    float* ws   = (float*)d_ws;
    float* cell = ws;                 // 1024
    float* aemb = ws + 1024;          // 8
    int*   aidx = (int*)(ws + 1040);  // 1
    float* x    = ws + 1056;          // 4096*34 = 139264
    float* qkv  = x + SEQ * DIM;      // 4096*102 = 417792
    float* o    = qkv + SEQ * QKV_LD; // 139264

    wm_prep<<<1, 256, 0, stream>>>(obs, action, c1w, c1b, c2w, c2b, aw, ab, cell, aemb, aidx);
    wm_seq<<<16, 256, 0, stream>>>(cell, x);
    for (int l = 0; l < 2; ++l) {
        const int base = 6 + l * 12;
        const float* in_w  = (const float*)d_in[base + 0];
        const float* in_b  = (const float*)d_in[base + 1];
        const float* out_w = (const float*)d_in[base + 2];
        const float* out_b = (const float*)d_in[base + 3];
        const float* ff1_w = (const float*)d_in[base + 4];
        const float* ff1_b = (const float*)d_in[base + 5];
        const float* ff2_w = (const float*)d_in[base + 6];
        const float* ff2_b = (const float*)d_in[base + 7];
        const float* ln1g  = (const float*)d_in[base + 8];
        const float* ln1b  = (const float*)d_in[base + 9];
        const float* ln2g  = (const float*)d_in[base + 10];
        const float* ln2b  = (const float*)d_in[base + 11];

        wm_qkv<<<SEQ * QKV_LD / 256, 256, 0, stream>>>(x, in_w, in_b, qkv);
        wm_attn<<<dim3(SEQ / 16, NHEAD), 256, 0, stream>>>(qkv, o);
        wm_projln<<<SEQ / 4, 256, 0, stream>>>(x, o, out_w, out_b, ln1g, ln1b);
        wm_ff<<<SEQ / 16, 256, 0, stream>>>(x, ff1_w, ff1_b, ff2_w, ff2_b, ln2g, ln2b);
    }
    wm_final<<<1, 64, 0, stream>>>(x, aidx, aemb, hw, hb, (float*)d_out);
}

// Round 3
// 388.425 us; speedup vs baseline: 1.6236x; 1.6236x over previous
//
#include <hip/hip_runtime.h>
#include <math.h>

// Problem constants
#define SEQ 4096          // N*N tokens
#define DIM 34
#define NHEAD 2
#define HD 17
#define FFDIM 2048
// (1/sqrt(17)) * log2(e): fold softmax scale + exp2 conversion into Q
#define SC2 0.34990494f

#define EXP2F(x) __builtin_amdgcn_exp2f(x)

typedef unsigned short u16;
typedef __attribute__((ext_vector_type(8))) short bf16x8;
typedef __attribute__((ext_vector_type(4))) float f32x4;

__device__ inline u16 f2bf(float f) {
    uint32_t u = __builtin_bit_cast(uint32_t, f);
    u += 0x7fffu + ((u >> 16) & 1u);
    return (u16)(u >> 16);
}
__device__ inline uint32_t pack2(float a, float b) {
    uint32_t ua = __builtin_bit_cast(uint32_t, a);
    ua += 0x7fffu + ((ua >> 16) & 1u);
    uint32_t ub = __builtin_bit_cast(uint32_t, b);
    ub += 0x7fffu + ((ub >> 16) & 1u);
    return (ua >> 16) | (ub & 0xffff0000u);
}

// ---------------------------------------------------------------------------
// Kernel 1: conv1 -> relu -> conv2 -> relu -> cell[64][16]; agent_idx; a_emb
// ---------------------------------------------------------------------------
__global__ __launch_bounds__(256) void wm_prep(
    const float* __restrict__ obs, const int* __restrict__ action,
    const float* __restrict__ c1w, const float* __restrict__ c1b,
    const float* __restrict__ c2w, const float* __restrict__ c2b,
    const float* __restrict__ aw,  const float* __restrict__ ab,
    float* __restrict__ cell, float* __restrict__ aemb, int* __restrict__ agent_idx)
{
    __shared__ float h1[16][64];
    const int tid = threadIdx.x;
    for (int e = tid; e < 1024; e += 256) {
        int o = e >> 6, y = (e >> 3) & 7, xx = e & 7;
        float a = c1b[o];
        for (int i = 0; i < 2; ++i)
            for (int ky = 0; ky < 3; ++ky) {
                int iy = y + ky - 1;
                if (iy < 0 || iy > 7) continue;
                for (int kx = 0; kx < 3; ++kx) {
                    int ix = xx + kx - 1;
                    if (ix < 0 || ix > 7) continue;
                    a += obs[i*64 + iy*8 + ix] * c1w[((o*2 + i)*3 + ky)*3 + kx];
                }
            }
        h1[o][y*8 + xx] = fmaxf(a, 0.f);
    }
    __syncthreads();
    for (int e = tid; e < 1024; e += 256) {
        int o = e >> 6, n = e & 63, y = n >> 3, xx = n & 7;
        float a = c2b[o];
        for (int i = 0; i < 16; ++i)
            for (int ky = 0; ky < 3; ++ky) {
                int iy = y + ky - 1;
                if (iy < 0 || iy > 7) continue;
                for (int kx = 0; kx < 3; ++kx) {
                    int ix = xx + kx - 1;
                    if (ix < 0 || ix > 7) continue;
                    a += h1[i][iy*8 + ix] * c2w[((o*16 + i)*3 + ky)*3 + kx];
                }
            }
        cell[n*16 + o] = fmaxf(a, 0.f);
    }
    if (tid < 64) {
        float v = obs[tid];
        float mx = v;
        for (int off = 32; off; off >>= 1) mx = fmaxf(mx, __shfl_xor(mx, off));
        unsigned long long mask = __ballot(v == mx);
        if (tid == 0) *agent_idx = (int)(__ffsll(mask) - 1);
    }
    if (tid >= 64 && tid < 72) {
        int k = tid - 64;
        int act = *action;
        aemb[k] = fmaxf(aw[k*4 + act] + ab[k], 0.f);
    }
}

// ---------------------------------------------------------------------------
// Kernel 2: build seq [4096][34]
// ---------------------------------------------------------------------------
__global__ __launch_bounds__(256) void wm_seq(const float* __restrict__ cell,
                                              float* __restrict__ x)
{
    __shared__ float cs[64][16];
    const int tid = threadIdx.x;
    for (int e = tid; e < 1024; e += 256) cs[e >> 4][e & 15] = cell[e];
    __syncthreads();
    const int t0 = blockIdx.x * 256;
    for (int e = tid; e < 256 * DIM; e += 256) {
        int t = t0 + e / DIM, d = e % DIM;
        int i = t >> 6, j = t & 63;
        float v;
        if (d < 16)       v = cs[i][d];
        else if (d < 32)  v = cs[j][d - 16];
        else if (d == 32) v = (float)((i >> 3) - (j >> 3)) * (1.0f / 3.5f);
        else              v = (float)((i & 7) - (j & 7)) * (1.0f / 3.5f);
        x[t0 * DIM + e] = v;
    }
}

// ---------------------------------------------------------------------------
// Kernel 3: qkv projection -> MFMA-ready bf16 layouts.
//  Qb[h][t][32] bf16 (dims 17..31 zero, scale*log2e folded in)
//  Kb[h][t][32] bf16 (dims 17..31 zero)
//  Vc[h][c][g][d][i] bf16 : V[key=c*32+g*8+i][d] for d<16 (PV A-fragment layout)
//  V16[h][t] bf16 : V[t][16]
// slot map: 0..63 Q(h=slot>>5,hs=slot&31), 64..127 K, 128..161 V(h,dd)
// ---------------------------------------------------------------------------
__global__ __launch_bounds__(256) void wm_qkv2(const float* __restrict__ x,
        const float* __restrict__ w, const float* __restrict__ b,
        u16* __restrict__ Qb, u16* __restrict__ Kb,
        u16* __restrict__ Vc, u16* __restrict__ V16)
{
    int gid = blockIdx.x * 256 + threadIdx.x;
    int t = gid & (SEQ - 1);
    int slot = gid >> 12;
    if (slot < 128) {
        int isK = slot >> 6;
        int hs  = slot & 31;
        int h   = (slot >> 5) & 1;
        float val = 0.f;
        if (hs < HD) {
            int row = isK*DIM + h*HD + hs;
            const float* wr = w + row*DIM;
            const float* xr = x + t*DIM;
            float a = b[row];
            #pragma unroll
            for (int d = 0; d < DIM; ++d) a = fmaf(xr[d], wr[d], a);
            val = isK ? a : a * SC2;
        }
        u16* dst = isK ? Kb : Qb;
        dst[(((size_t)h*SEQ + t) << 5) + hs] = f2bf(val);
    } else {
        int s = slot - 128;
        int h = s / HD, dd = s % HD;
        int row = 2*DIM + h*HD + dd;
        const float* wr = w + row*DIM;
        const float* xr = x + t*DIM;
        float a = b[row];
        #pragma unroll
        for (int d = 0; d < DIM; ++d) a = fmaf(xr[d], wr[d], a);
        u16 v = f2bf(a);
        if (dd == 16) V16[h*SEQ + t] = v;
        else {
            int c = t >> 5, g = (t >> 3) & 3, i = t & 7;
            Vc[((((size_t)h*128 + c)*4 + g)*16 + dd)*8 + i] = v;
        }
    }
}

// ---------------------------------------------------------------------------
// Kernel 4: MFMA flash attention.
// Block: 256 thr = 4 waves. Each wave: 16 queries (qt*16..+15) x 1024 keys.
// QK^T swapped (A=K, B=Q) so score col = lane&15 = query -> m/l lane-local.
// PV computed as O^T = V^T . P (A = V^T fragment from Vc) so O col = query too.
// Cross-wave combine of (m, l, O) through LDS at the end.
// ---------------------------------------------------------------------------
__global__ __launch_bounds__(256) void wm_attn2(const u16* __restrict__ Qb,
        const u16* __restrict__ Kb, const u16* __restrict__ Vc,
        const u16* __restrict__ V16, float* __restrict__ o)
{
    const int qt = blockIdx.x, h = blockIdx.y;
    const int tid = threadIdx.x;
    const int wv = tid >> 6, l = tid & 63;
    const int q = l & 15, g = l >> 4;

    __shared__ float red[3][64][8];

    const u16* Qh = Qb + (((size_t)h*SEQ + qt*16 + q) << 5) + 8*g;
    const u16* Kh = Kb + ((size_t)h*SEQ << 5);
    const u16* Vh = Vc + (size_t)h*128*512;
    const u16* V6 = V16 + (size_t)h*SEQ;

    const bf16x8 qf = *(const bf16x8*)Qh;
    const f32x4 zero4 = {0.f, 0.f, 0.f, 0.f};

    f32x4 olo = zero4, ohi = zero4;
    float m = -INFINITY, lsum = 0.f;

    for (int c = wv*32; c < wv*32 + 32; ++c) {
        const int k0 = c * 32;
        bf16x8 kf0 = *(const bf16x8*)(Kh + ((size_t)(k0 + q) << 5) + 8*g);
        bf16x8 kf1 = *(const bf16x8*)(Kh + ((size_t)(k0 + 16 + q) << 5) + 8*g);
        f32x4 s0 = __builtin_amdgcn_mfma_f32_16x16x32_bf16(kf0, qf, zero4, 0, 0, 0);
        f32x4 s1 = __builtin_amdgcn_mfma_f32_16x16x32_bf16(kf1, qf, zero4, 0, 0, 0);
        // scores (log2 units): s0 reg r = key k0+4g+r, s1 reg r = key k0+16+4g+r, col q
        float tm = fmaxf(fmaxf(fmaxf(s0[0], s0[1]), fmaxf(s0[2], s0[3])),
                         fmaxf(fmaxf(s1[0], s1[1]), fmaxf(s1[2], s1[3])));
        tm = fmaxf(tm, __shfl_xor(tm, 16));
        tm = fmaxf(tm, __shfl_xor(tm, 32));
        float newm = fmaxf(m, tm);
        float fac = EXP2F(m - newm);
        m = newm;
        float p00 = EXP2F(s0[0] - m), p01 = EXP2F(s0[1] - m);
        float p02 = EXP2F(s0[2] - m), p03 = EXP2F(s0[3] - m);
        float p10 = EXP2F(s1[0] - m), p11 = EXP2F(s1[1] - m);
        float p12 = EXP2F(s1[2] - m), p13 = EXP2F(s1[3] - m);
        float ts = ((p00 + p01) + (p02 + p03)) + ((p10 + p11) + (p12 + p13));
        ts += __shfl_xor(ts, 16);
        ts += __shfl_xor(ts, 32);
        lsum = lsum * fac + ts;
        olo[0] *= fac; olo[1] *= fac; olo[2] *= fac; olo[3] *= fac;
        ohi[0] *= fac; ohi[1] *= fac; ohi[2] *= fac; ohi[3] *= fac;
        // P -> bf16, redistribute into PV B-fragment: lane (q,g) needs keys 8g..8g+7 at col q
        uint32_t a0t0 = pack2(p00, p01), a1t0 = pack2(p02, p03);
        uint32_t a0t1 = pack2(p10, p11), a1t1 = pack2(p12, p13);
        int srcA = q + 32*(g & 1);
        int srcB = srcA + 16;
        uint32_t w0a = (uint32_t)__shfl((int)a0t0, srcA), w0b = (uint32_t)__shfl((int)a0t1, srcA);
        uint32_t w1a = (uint32_t)__shfl((int)a1t0, srcA), w1b = (uint32_t)__shfl((int)a1t1, srcA);
        uint32_t w2a = (uint32_t)__shfl((int)a0t0, srcB), w2b = (uint32_t)__shfl((int)a0t1, srcB);
        uint32_t w3a = (uint32_t)__shfl((int)a1t0, srcB), w3b = (uint32_t)__shfl((int)a1t1, srcB);
        const bool hi = (g >= 2);
        union { uint32_t u[4]; bf16x8 v; } pu;
        pu.u[0] = hi ? w0b : w0a;
        pu.u[1] = hi ? w1b : w1a;
        pu.u[2] = hi ? w2b : w2a;
        pu.u[3] = hi ? w3b : w3a;
        bf16x8 pf = pu.v;
        // V fragments: A row = l&15 = d (contiguous 16B thanks to Vc swizzle)
        bf16x8 vf = *(const bf16x8*)(Vh + (size_t)(c*4 + g)*128 + q*8);
        bf16x8 v6 = {};
        if (q == 0) v6 = *(const bf16x8*)(V6 + k0 + 8*g);
        olo = __builtin_amdgcn_mfma_f32_16x16x32_bf16(vf, pf, olo, 0, 0, 0);
        ohi = __builtin_amdgcn_mfma_f32_16x16x32_bf16(v6, pf, ohi, 0, 0, 0);
    }

    if (wv) {
        float* r = red[wv - 1][l];
        r[0] = m; r[1] = lsum;
        r[2] = olo[0]; r[3] = olo[1]; r[4] = olo[2]; r[5] = olo[3];
        r[6] = ohi[0];
    }
    __syncthreads();
    if (wv == 0) {
        float M = m;
        #pragma unroll
        for (int p = 0; p < 3; ++p) M = fmaxf(M, red[p][l][0]);
        float f = EXP2F(m - M);
        float lt = lsum * f;
        float o0 = olo[0]*f, o1 = olo[1]*f, o2 = olo[2]*f, o3 = olo[3]*f, o6 = ohi[0]*f;
        #pragma unroll
        for (int p = 0; p < 3; ++p) {
            float* r = red[p][l];
            float fp = EXP2F(r[0] - M);
            lt += r[1] * fp;
            o0 += r[2]*fp; o1 += r[3]*fp; o2 += r[4]*fp; o3 += r[5]*fp; o6 += r[6]*fp;
        }
        float inv = 1.f / lt;
        float* orow = o + (size_t)(qt*16 + q)*DIM + h*HD;
        orow[4*g + 0] = o0*inv; orow[4*g + 1] = o1*inv;
        orow[4*g + 2] = o2*inv; orow[4*g + 3] = o3*inv;
        if (g == 0) orow[16] = o6*inv;
    }
}

// ---------------------------------------------------------------------------
// Kernel 5: x = LN(x + o @ out_w.T + out_b). One wave per token.
// ---------------------------------------------------------------------------
__global__ __launch_bounds__(256) void wm_projln(float* __restrict__ x,
                                                 const float* __restrict__ o,
                                                 const float* __restrict__ w,
                                                 const float* __restrict__ b,
                                                 const float* __restrict__ g,
                                                 const float* __restrict__ be)
{
    const int wv = threadIdx.x >> 6, lane = threadIdx.x & 63;
    const int t = blockIdx.x * 4 + wv;
    const float* orow = o + t * DIM;
    float r = 0.f;
    if (lane < DIM) {
        float accv = b[lane];
        const float* wr = w + lane * DIM;
        #pragma unroll
        for (int e = 0; e < DIM; ++e) accv = fmaf(orow[e], wr[e], accv);
        r = x[t*DIM + lane] + accv;
    }
    float s1 = r, s2 = r * r;
    for (int off = 32; off; off >>= 1) { s1 += __shfl_xor(s1, off); s2 += __shfl_xor(s2, off); }
    float mean = s1 * (1.0f / DIM);
    float var  = s2 * (1.0f / DIM) - mean * mean;
    float rstd = rsqrtf(var + 1e-5f);
    if (lane < DIM) x[t*DIM + lane] = (r - mean) * rstd * g[lane] + be[lane];
}

// ---------------------------------------------------------------------------
// Kernel 6: fused FFN + residual + LN2, in-place on x.
// ---------------------------------------------------------------------------
__global__ __launch_bounds__(256) void wm_ff(float* __restrict__ x,
                                             const float* __restrict__ w1,
                                             const float* __restrict__ b1,
                                             const float* __restrict__ w2,
                                             const float* __restrict__ b2,
                                             const float* __restrict__ g,
                                             const float* __restrict__ be)
{
    __shared__ float xs[16][DIM];
    __shared__ float hs[16][256];
    __shared__ float ys[16][DIM];
    __shared__ float stats[16][2];
    const int tid = threadIdx.x;
    const int t0 = blockIdx.x * 16;

    for (int e = tid; e < 16 * DIM; e += 256) xs[e / DIM][e % DIM] = x[t0*DIM + e];

    const int d0  = tid % DIM, tp0 = tid / DIM;
    const int s1v = tid + 256;
    const int d1  = s1v % DIM, tp1 = s1v / DIM;
    const bool has1 = (s1v < 272);
    float y00 = 0.f, y01 = 0.f, y10 = 0.f, y11 = 0.f;
    __syncthreads();

    for (int ch = 0; ch < FFDIM / 256; ++ch) {
        const int f = ch * 256 + tid;
        const float* wr = w1 + f * DIM;
        float wreg[DIM];
        #pragma unroll
        for (int d = 0; d < DIM; ++d) wreg[d] = wr[d];
        const float bb = b1[f];
        if (ch) __syncthreads();
        for (int t = 0; t < 16; ++t) {
            float a = bb;
            #pragma unroll
            for (int d = 0; d < DIM; ++d) a = fmaf(xs[t][d], wreg[d], a);
            hs[t][tid] = fmaxf(a, 0.f);
        }
        __syncthreads();
        {
            const float4* wv = (const float4*)(w2 + d0*FFDIM + ch*256);
            const float4* h0 = (const float4*)hs[tp0*2];
            const float4* h1 = (const float4*)hs[tp0*2 + 1];
            for (int f4 = 0; f4 < 64; ++f4) {
                float4 ww = wv[f4];
                float4 a = h0[f4], b4 = h1[f4];
                y00 += a.x*ww.x + a.y*ww.y + a.z*ww.z + a.w*ww.w;
                y01 += b4.x*ww.x + b4.y*ww.y + b4.z*ww.z + b4.w*ww.w;
            }
        }
        if (has1) {
            const float4* wv = (const float4*)(w2 + d1*FFDIM + ch*256);
            const float4* h0 = (const float4*)hs[tp1*2];
            const float4* h1 = (const float4*)hs[tp1*2 + 1];
            for (int f4 = 0; f4 < 64; ++f4) {
                float4 ww = wv[f4];
                float4 a = h0[f4], b4 = h1[f4];
                y10 += a.x*ww.x + a.y*ww.y + a.z*ww.z + a.w*ww.w;
                y11 += b4.x*ww.x + b4.y*ww.y + b4.z*ww.z + b4.w*ww.w;
            }
        }
    }
    __syncthreads();
    ys[tp0*2][d0]     = xs[tp0*2][d0]     + y00 + b2[d0];
    ys[tp0*2 + 1][d0] = xs[tp0*2 + 1][d0] + y01 + b2[d0];
    if (has1) {
        ys[tp1*2][d1]     = xs[tp1*2][d1]     + y10 + b2[d1];
        ys[tp1*2 + 1][d1] = xs[tp1*2 + 1][d1] + y11 + b2[d1];
    }
    __syncthreads();
    if (tid < 16) {
        float s1 = 0.f, s2 = 0.f;
        #pragma unroll
        for (int d = 0; d < DIM; ++d) { float v = ys[tid][d]; s1 += v; s2 += v * v; }
        float mean = s1 * (1.0f / DIM);
        float var  = s2 * (1.0f / DIM) - mean * mean;
        stats[tid][0] = mean;
        stats[tid][1] = rsqrtf(var + 1e-5f);
    }
    __syncthreads();
    for (int e = tid; e < 16 * DIM; e += 256) {
        int t = e / DIM, d = e % DIM;
        x[t0*DIM + e] = (ys[t][d] - stats[t][0]) * stats[t][1] * g[d] + be[d];
    }
}

// ---------------------------------------------------------------------------
// Kernel 7: final head
// ---------------------------------------------------------------------------
__global__ __launch_bounds__(64) void wm_final(const float* __restrict__ x,
                                               const int* __restrict__ agent_idx,
                                               const float* __restrict__ aemb,
                                               const float* __restrict__ hw,
                                               const float* __restrict__ hb,
                                               float* __restrict__ out)
{
    __shared__ float hv[DIM];
    const int tid = threadIdx.x;
    const int ai = *agent_idx;
    if (tid < DIM) {
        float s = 0.f;
        for (int r = 0; r < 64; ++r) s += x[(ai*64 + r)*DIM + tid];
        hv[tid] = s * (1.0f / 64.0f);
    }
    __syncthreads();
    if (tid < 16) {
        float a = hb[tid];
        #pragma unroll
        for (int d = 0; d < DIM; ++d) a = fmaf(hv[d], hw[tid*42 + d], a);
        #pragma unroll
        for (int j = 0; j < 8; ++j) a = fmaf(aemb[j], hw[tid*42 + DIM + j], a);
        out[tid] = a;
    }
}

// ---------------------------------------------------------------------------
extern "C" void kernel_launch(void* const* d_in, const int* in_sizes, int n_in,
                              void* d_out, int out_size, void* d_ws, size_t ws_size,
                              hipStream_t stream)
{
    const float* obs    = (const float*)d_in[0];
    const int*   action = (const int*)  d_in[1];
    const float* c1w = (const float*)d_in[2];
    const float* c1b = (const float*)d_in[3];
    const float* c2w = (const float*)d_in[4];
    const float* c2b = (const float*)d_in[5];
    const float* aw  = (const float*)d_in[30];
    const float* ab  = (const float*)d_in[31];
    const float* hw  = (const float*)d_in[32];
    const float* hb  = (const float*)d_in[33];

    float* ws   = (float*)d_ws;
    float* cell = ws;                       // 1024
    float* aemb = ws + 1024;                // 8
    int*   aidx = (int*)(ws + 1040);        // 1
    float* x    = ws + 1056;                // 4096*34
    float* o    = x + SEQ * DIM;            // 4096*34
    u16*   Qb   = (u16*)(o + SEQ * DIM);    // 2*4096*32 bf16
    u16*   Kb   = Qb + 2 * SEQ * 32;        // 2*4096*32 bf16
    u16*   Vc   = Kb + 2 * SEQ * 32;        // 2*128*4*16*8 bf16
    u16*   V16  = Vc + 2 * 128 * 512;       // 2*4096 bf16

    wm_prep<<<1, 256, 0, stream>>>(obs, action, c1w, c1b, c2w, c2b, aw, ab, cell, aemb, aidx);
    wm_seq<<<16, 256, 0, stream>>>(cell, x);
    for (int l = 0; l < 2; ++l) {
        const int base = 6 + l * 12;
        const float* in_w  = (const float*)d_in[base + 0];
        const float* in_b  = (const float*)d_in[base + 1];
        const float* out_w = (const float*)d_in[base + 2];
        const float* out_b = (const float*)d_in[base + 3];
        const float* ff1_w = (const float*)d_in[base + 4];
        const float* ff1_b = (const float*)d_in[base + 5];
        const float* ff2_w = (const float*)d_in[base + 6];
        const float* ff2_b = (const float*)d_in[base + 7];
        const float* ln1g  = (const float*)d_in[base + 8];
        const float* ln1b  = (const float*)d_in[base + 9];
        const float* ln2g  = (const float*)d_in[base + 10];
        const float* ln2b  = (const float*)d_in[base + 11];

        wm_qkv2<<<162 * (SEQ / 256), 256, 0, stream>>>(x, in_w, in_b, Qb, Kb, Vc, V16);
        wm_attn2<<<dim3(SEQ / 16, NHEAD), 256, 0, stream>>>(Qb, Kb, Vc, V16, o);
        wm_projln<<<SEQ / 4, 256, 0, stream>>>(x, o, out_w, out_b, ln1g, ln1b);
        wm_ff<<<SEQ / 16, 256, 0, stream>>>(x, ff1_w, ff1_b, ff2_w, ff2_b, ln2g, ln2b);
    }
    wm_final<<<1, 64, 0, stream>>>(x, aidx, aemb, hw, hb, (float*)d_out);
}

// Round 4
// 183.534 us; speedup vs baseline: 3.4362x; 2.1164x over previous
//
#include <hip/hip_runtime.h>
#include <math.h>

// Problem constants
#define SEQ 4096          // N*N tokens
#define DIM 34
#define NHEAD 2
#define HD 17
#define FFDIM 2048
// (1/sqrt(17)) * log2(e): fold softmax scale + exp2 conversion into Q
#define SC2 0.34990494f

#define EXP2F(x) __builtin_amdgcn_exp2f(x)
#define MFMA16(a, b, c) __builtin_amdgcn_mfma_f32_16x16x32_bf16(a, b, c, 0, 0, 0)

typedef unsigned short u16;
typedef __attribute__((ext_vector_type(8))) short bf16x8;
typedef __attribute__((ext_vector_type(4))) float f32x4;

__device__ inline u16 f2bf(float f) {
    uint32_t u = __builtin_bit_cast(uint32_t, f);
    u += 0x7fffu + ((u >> 16) & 1u);
    return (u16)(u >> 16);
}
__device__ inline uint32_t pack2(float a, float b) {
    uint32_t ua = __builtin_bit_cast(uint32_t, a);
    ua += 0x7fffu + ((ua >> 16) & 1u);
    uint32_t ub = __builtin_bit_cast(uint32_t, b);
    ub += 0x7fffu + ((ub >> 16) & 1u);
    return (ua >> 16) | (ub & 0xffff0000u);
}

// ---------------------------------------------------------------------------
// Kernel 1: conv1 -> relu -> conv2 -> relu -> cell[64][16]; agent_idx; a_emb
// ---------------------------------------------------------------------------
__global__ __launch_bounds__(256) void wm_prep(
    const float* __restrict__ obs, const int* __restrict__ action,
    const float* __restrict__ c1w, const float* __restrict__ c1b,
    const float* __restrict__ c2w, const float* __restrict__ c2b,
    const float* __restrict__ aw,  const float* __restrict__ ab,
    float* __restrict__ cell, float* __restrict__ aemb, int* __restrict__ agent_idx)
{
    __shared__ float h1[16][64];
    const int tid = threadIdx.x;
    for (int e = tid; e < 1024; e += 256) {
        int o = e >> 6, y = (e >> 3) & 7, xx = e & 7;
        float a = c1b[o];
        for (int i = 0; i < 2; ++i)
            for (int ky = 0; ky < 3; ++ky) {
                int iy = y + ky - 1;
                if (iy < 0 || iy > 7) continue;
                for (int kx = 0; kx < 3; ++kx) {
                    int ix = xx + kx - 1;
                    if (ix < 0 || ix > 7) continue;
                    a += obs[i*64 + iy*8 + ix] * c1w[((o*2 + i)*3 + ky)*3 + kx];
                }
            }
        h1[o][y*8 + xx] = fmaxf(a, 0.f);
    }
    __syncthreads();
    for (int e = tid; e < 1024; e += 256) {
        int o = e >> 6, n = e & 63, y = n >> 3, xx = n & 7;
        float a = c2b[o];
        for (int i = 0; i < 16; ++i)
            for (int ky = 0; ky < 3; ++ky) {
                int iy = y + ky - 1;
                if (iy < 0 || iy > 7) continue;
                for (int kx = 0; kx < 3; ++kx) {
                    int ix = xx + kx - 1;
                    if (ix < 0 || ix > 7) continue;
                    a += h1[i][iy*8 + ix] * c2w[((o*16 + i)*3 + ky)*3 + kx];
                }
            }
        cell[n*16 + o] = fmaxf(a, 0.f);
    }
    if (tid < 64) {
        float v = obs[tid];
        float mx = v;
        for (int off = 32; off; off >>= 1) mx = fmaxf(mx, __shfl_xor(mx, off));
        unsigned long long mask = __ballot(v == mx);
        if (tid == 0) *agent_idx = (int)(__ffsll(mask) - 1);
    }
    if (tid >= 64 && tid < 72) {
        int k = tid - 64;
        int act = *action;
        aemb[k] = fmaxf(aw[k*4 + act] + ab[k], 0.f);
    }
}

// ---------------------------------------------------------------------------
// Kernel 2: build seq [4096][34]
// ---------------------------------------------------------------------------
__global__ __launch_bounds__(256) void wm_seq(const float* __restrict__ cell,
                                              float* __restrict__ x)
{
    __shared__ float cs[64][16];
    const int tid = threadIdx.x;
    for (int e = tid; e < 1024; e += 256) cs[e >> 4][e & 15] = cell[e];
    __syncthreads();
    const int t0 = blockIdx.x * 256;
    for (int e = tid; e < 256 * DIM; e += 256) {
        int t = t0 + e / DIM, d = e % DIM;
        int i = t >> 6, j = t & 63;
        float v;
        if (d < 16)       v = cs[i][d];
        else if (d < 32)  v = cs[j][d - 16];
        else if (d == 32) v = (float)((i >> 3) - (j >> 3)) * (1.0f / 3.5f);
        else              v = (float)((i & 7) - (j & 7)) * (1.0f / 3.5f);
        x[t0 * DIM + e] = v;
    }
}

// ---------------------------------------------------------------------------
// Kernel 2b: repack FFN weights to bf16, both layers.
//  W1b[2048][64]: cols 0..33 = w1[n][k], col 34 = b1[n], rest 0
//  W2b[48][2048]: rows 0..33 = w2[n][k], rest 0
// ---------------------------------------------------------------------------
#define W1B_ELEMS (FFDIM * 64)       // 131072
#define W2B_ELEMS (48 * FFDIM)       // 98304
__global__ __launch_bounds__(256) void wm_wconv(
    const float* __restrict__ w1a, const float* __restrict__ b1a, const float* __restrict__ w2a,
    const float* __restrict__ w1b, const float* __restrict__ b1b, const float* __restrict__ w2b,
    u16* __restrict__ W1A, u16* __restrict__ W2A,
    u16* __restrict__ W1B, u16* __restrict__ W2B)
{
    int id = blockIdx.x * 256 + threadIdx.x;
    const int half = W1B_ELEMS + W2B_ELEMS;
    const float* w1 = w1a; const float* b1 = b1a; const float* w2 = w2a;
    u16* W1 = W1A; u16* W2 = W2A;
    if (id >= half) { id -= half; w1 = w1b; b1 = b1b; w2 = w2b; W1 = W1B; W2 = W2B; }
    if (id < W1B_ELEMS) {
        int n = id >> 6, c = id & 63;
        float v = (c < DIM) ? w1[n*DIM + c] : ((c == DIM) ? b1[n] : 0.f);
        W1[id] = f2bf(v);
    } else {
        int e = id - W1B_ELEMS;
        int n = e >> 11;
        float v = (n < DIM) ? w2[(n << 11) + (e & 2047)] : 0.f;
        W2[e] = f2bf(v);
    }
}

// ---------------------------------------------------------------------------
// Kernel 3: qkv projection -> MFMA-ready bf16 layouts.
// ---------------------------------------------------------------------------
__global__ __launch_bounds__(256) void wm_qkv2(const float* __restrict__ x,
        const float* __restrict__ w, const float* __restrict__ b,
        u16* __restrict__ Qb, u16* __restrict__ Kb,
        u16* __restrict__ Vc, u16* __restrict__ V16)
{
    int gid = blockIdx.x * 256 + threadIdx.x;
    int t = gid & (SEQ - 1);
    int slot = gid >> 12;
    if (slot < 128) {
        int isK = slot >> 6;
        int hs  = slot & 31;
        int h   = (slot >> 5) & 1;
        float val = 0.f;
        if (hs < HD) {
            int row = isK*DIM + h*HD + hs;
            const float* wr = w + row*DIM;
            const float* xr = x + t*DIM;
            float a = b[row];
            #pragma unroll
            for (int d = 0; d < DIM; ++d) a = fmaf(xr[d], wr[d], a);
            val = isK ? a : a * SC2;
        }
        u16* dst = isK ? Kb : Qb;
        dst[(((size_t)h*SEQ + t) << 5) + hs] = f2bf(val);
    } else {
        int s = slot - 128;
        int h = s / HD, dd = s % HD;
        int row = 2*DIM + h*HD + dd;
        const float* wr = w + row*DIM;
        const float* xr = x + t*DIM;
        float a = b[row];
        #pragma unroll
        for (int d = 0; d < DIM; ++d) a = fmaf(xr[d], wr[d], a);
        u16 v = f2bf(a);
        if (dd == 16) V16[h*SEQ + t] = v;
        else {
            int c = t >> 5, g = (t >> 3) & 3, i = t & 7;
            Vc[((((size_t)h*128 + c)*4 + g)*16 + dd)*8 + i] = v;
        }
    }
}

// ---------------------------------------------------------------------------
// Kernel 4: MFMA flash attention (unchanged from R3).
// ---------------------------------------------------------------------------
__global__ __launch_bounds__(256) void wm_attn2(const u16* __restrict__ Qb,
        const u16* __restrict__ Kb, const u16* __restrict__ Vc,
        const u16* __restrict__ V16, float* __restrict__ o)
{
    const int qt = blockIdx.x, h = blockIdx.y;
    const int tid = threadIdx.x;
    const int wv = tid >> 6, l = tid & 63;
    const int q = l & 15, g = l >> 4;

    __shared__ float red[3][64][8];

    const u16* Qh = Qb + (((size_t)h*SEQ + qt*16 + q) << 5) + 8*g;
    const u16* Kh = Kb + ((size_t)h*SEQ << 5);
    const u16* Vh = Vc + (size_t)h*128*512;
    const u16* V6 = V16 + (size_t)h*SEQ;

    const bf16x8 qf = *(const bf16x8*)Qh;
    const f32x4 zero4 = {0.f, 0.f, 0.f, 0.f};

    f32x4 olo = zero4, ohi = zero4;
    float m = -INFINITY, lsum = 0.f;

    for (int c = wv*32; c < wv*32 + 32; ++c) {
        const int k0 = c * 32;
        bf16x8 kf0 = *(const bf16x8*)(Kh + ((size_t)(k0 + q) << 5) + 8*g);
        bf16x8 kf1 = *(const bf16x8*)(Kh + ((size_t)(k0 + 16 + q) << 5) + 8*g);
        f32x4 s0 = MFMA16(kf0, qf, zero4);
        f32x4 s1 = MFMA16(kf1, qf, zero4);
        float tm = fmaxf(fmaxf(fmaxf(s0[0], s0[1]), fmaxf(s0[2], s0[3])),
                         fmaxf(fmaxf(s1[0], s1[1]), fmaxf(s1[2], s1[3])));
        tm = fmaxf(tm, __shfl_xor(tm, 16));
        tm = fmaxf(tm, __shfl_xor(tm, 32));
        float newm = fmaxf(m, tm);
        float fac = EXP2F(m - newm);
        m = newm;
        float p00 = EXP2F(s0[0] - m), p01 = EXP2F(s0[1] - m);
        float p02 = EXP2F(s0[2] - m), p03 = EXP2F(s0[3] - m);
        float p10 = EXP2F(s1[0] - m), p11 = EXP2F(s1[1] - m);
        float p12 = EXP2F(s1[2] - m), p13 = EXP2F(s1[3] - m);
        float ts = ((p00 + p01) + (p02 + p03)) + ((p10 + p11) + (p12 + p13));
        ts += __shfl_xor(ts, 16);
        ts += __shfl_xor(ts, 32);
        lsum = lsum * fac + ts;
        olo[0] *= fac; olo[1] *= fac; olo[2] *= fac; olo[3] *= fac;
        ohi[0] *= fac; ohi[1] *= fac; ohi[2] *= fac; ohi[3] *= fac;
        uint32_t a0t0 = pack2(p00, p01), a1t0 = pack2(p02, p03);
        uint32_t a0t1 = pack2(p10, p11), a1t1 = pack2(p12, p13);
        int srcA = q + 32*(g & 1);
        int srcB = srcA + 16;
        uint32_t w0a = (uint32_t)__shfl((int)a0t0, srcA), w0b = (uint32_t)__shfl((int)a0t1, srcA);
        uint32_t w1a = (uint32_t)__shfl((int)a1t0, srcA), w1b = (uint32_t)__shfl((int)a1t1, srcA);
        uint32_t w2a = (uint32_t)__shfl((int)a0t0, srcB), w2b = (uint32_t)__shfl((int)a0t1, srcB);
        uint32_t w3a = (uint32_t)__shfl((int)a1t0, srcB), w3b = (uint32_t)__shfl((int)a1t1, srcB);
        const bool hi = (g >= 2);
        union { uint32_t u[4]; bf16x8 v; } pu;
        pu.u[0] = hi ? w0b : w0a;
        pu.u[1] = hi ? w1b : w1a;
        pu.u[2] = hi ? w2b : w2a;
        pu.u[3] = hi ? w3b : w3a;
        bf16x8 pf = pu.v;
        bf16x8 vf = *(const bf16x8*)(Vh + (size_t)(c*4 + g)*128 + q*8);
        bf16x8 v6 = {};
        if (q == 0) v6 = *(const bf16x8*)(V6 + k0 + 8*g);
        olo = MFMA16(vf, pf, olo);
        ohi = MFMA16(v6, pf, ohi);
    }

    if (wv) {
        float* r = red[wv - 1][l];
        r[0] = m; r[1] = lsum;
        r[2] = olo[0]; r[3] = olo[1]; r[4] = olo[2]; r[5] = olo[3];
        r[6] = ohi[0];
    }
    __syncthreads();
    if (wv == 0) {
        float M = m;
        #pragma unroll
        for (int p = 0; p < 3; ++p) M = fmaxf(M, red[p][l][0]);
        float f = EXP2F(m - M);
        float lt = lsum * f;
        float o0 = olo[0]*f, o1 = olo[1]*f, o2 = olo[2]*f, o3 = olo[3]*f, o6 = ohi[0]*f;
        #pragma unroll
        for (int p = 0; p < 3; ++p) {
            float* r = red[p][l];
            float fp = EXP2F(r[0] - M);
            lt += r[1] * fp;
            o0 += r[2]*fp; o1 += r[3]*fp; o2 += r[4]*fp; o3 += r[5]*fp; o6 += r[6]*fp;
        }
        float inv = 1.f / lt;
        float* orow = o + (size_t)(qt*16 + q)*DIM + h*HD;
        orow[4*g + 0] = o0*inv; orow[4*g + 1] = o1*inv;
        orow[4*g + 2] = o2*inv; orow[4*g + 3] = o3*inv;
        if (g == 0) orow[16] = o6*inv;
    }
}

// ---------------------------------------------------------------------------
// Kernel 5: x = LN(x + o @ out_w.T + out_b). One wave per token.
// ---------------------------------------------------------------------------
__global__ __launch_bounds__(256) void wm_projln(float* __restrict__ x,
                                                 const float* __restrict__ o,
                                                 const float* __restrict__ w,
                                                 const float* __restrict__ b,
                                                 const float* __restrict__ g,
                                                 const float* __restrict__ be)
{
    const int wv = threadIdx.x >> 6, lane = threadIdx.x & 63;
    const int t = blockIdx.x * 4 + wv;
    const float* orow = o + t * DIM;
    float r = 0.f;
    if (lane < DIM) {
        float accv = b[lane];
        const float* wr = w + lane * DIM;
        #pragma unroll
        for (int e = 0; e < DIM; ++e) accv = fmaf(orow[e], wr[e], accv);
        r = x[t*DIM + lane] + accv;
    }
    float s1 = r, s2 = r * r;
    for (int off = 32; off; off >>= 1) { s1 += __shfl_xor(s1, off); s2 += __shfl_xor(s2, off); }
    float mean = s1 * (1.0f / DIM);
    float var  = s2 * (1.0f / DIM) - mean * mean;
    float rstd = rsqrtf(var + 1e-5f);
    if (lane < DIM) x[t*DIM + lane] = (r - mean) * rstd * g[lane] + be[lane];
}

// ---------------------------------------------------------------------------
// Kernel 6: MFMA fused FFN + residual + LN2, in-place on x.
// Block: 16 tokens, 512 thr = 8 waves; wave owns 256 hidden (2 phases x 128).
// GEMM1: A = X (bf16, col34=1 for bias), B = W1b rows; C(m=token reg-dim,
// n=hidden lane-dim) -> relu -> bf16 -> wave-private swizzled LDS.
// GEMM2: A = H from LDS, B = W2b rows; acc[3] tiles (48 outs, 34 real).
// Epilogue: cross-wave reduce + residual + bias + LN.
// ---------------------------------------------------------------------------
__global__ __launch_bounds__(512) void wm_ff2(float* __restrict__ x,
        const u16* __restrict__ W1b, const u16* __restrict__ W2b,
        const float* __restrict__ b2, const float* __restrict__ g,
        const float* __restrict__ be)
{
    __shared__ u16 Hs[8][16][128];       // 32 KB, wave-private [16][128], XOR-swizzled
    __shared__ float red[8][16][52];     // 26.6 KB (52 pad: stride 208B, no bank repeat)
    __shared__ float ys[16][DIM];
    __shared__ float stats[16][2];
    const int tid = threadIdx.x, wv = tid >> 6, l = tid & 63;
    const int q = l & 15, g4 = l >> 4;
    const int t0 = blockIdx.x * 16;

    // A-fragments for GEMM1: token row = t0+q, k-slice = g4*8..+7 (and +32)
    const float* xr = x + (size_t)(t0 + q) * DIM;
    union { uint32_t u[4]; bf16x8 v; } a0, a1;
    #pragma unroll
    for (int j = 0; j < 4; ++j)
        a0.u[j] = pack2(xr[g4*8 + 2*j], xr[g4*8 + 2*j + 1]);
    a1.u[0] = 0; a1.u[1] = 0; a1.u[2] = 0; a1.u[3] = 0;
    if (g4 == 0) {
        a1.u[0] = pack2(xr[32], xr[33]);
        a1.u[1] = pack2(1.0f, 0.f);      // col 34 = bias slot
    }
    const f32x4 zero4 = {0.f, 0.f, 0.f, 0.f};

    f32x4 acc0 = zero4, acc1 = zero4, acc2 = zero4;
    for (int ph = 0; ph < 2; ++ph) {
        const int hb = wv*256 + ph*128;   // hidden base for this wave+phase
        // GEMM1: 8 n-tiles of 16
        #pragma unroll
        for (int nt = 0; nt < 8; ++nt) {
            const u16* brow = W1b + (size_t)(hb + nt*16 + q) * 64 + g4*8;
            bf16x8 b0 = *(const bf16x8*)brow;
            bf16x8 b1f = *(const bf16x8*)(brow + 32);
            f32x4 c = MFMA16(a0.v, b0, zero4);
            c = MFMA16(a1.v, b1f, c);
            #pragma unroll
            for (int r = 0; r < 4; ++r) {
                int m = 4*g4 + r;
                int byte = ((nt*16 + q) * 2) ^ ((m & 7) << 4);
                *(u16*)((char*)&Hs[wv][m][0] + byte) = f2bf(fmaxf(c[r], 0.f));
            }
        }
        __syncthreads();
        // GEMM2: K = this phase's 128 hidden
        #pragma unroll
        for (int ks = 0; ks < 4; ++ks) {
            int byte = (ks*64 + g4*16) ^ ((q & 7) << 4);
            bf16x8 af = *(const bf16x8*)((char*)&Hs[wv][q][0] + byte);
            const u16* bp = W2b + (size_t)q * FFDIM + hb + ks*32 + g4*8;
            acc0 = MFMA16(af, *(const bf16x8*)bp, acc0);
            acc1 = MFMA16(af, *(const bf16x8*)(bp + 16*FFDIM), acc1);
            acc2 = MFMA16(af, *(const bf16x8*)(bp + 32*FFDIM), acc2);
        }
        __syncthreads();   // Hs reads done before next phase overwrites
    }
    #pragma unroll
    for (int r = 0; r < 4; ++r) {
        red[wv][4*g4 + r][q]      = acc0[r];
        red[wv][4*g4 + r][16 + q] = acc1[r];
        red[wv][4*g4 + r][32 + q] = acc2[r];
    }
    __syncthreads();
    for (int e = tid; e < 16*DIM; e += 512) {
        int tt = e / DIM, d = e % DIM;
        float v = x[(size_t)(t0 + tt)*DIM + d] + b2[d];
        #pragma unroll
        for (int w = 0; w < 8; ++w) v += red[w][tt][d];
        ys[tt][d] = v;
    }
    __syncthreads();
    if (tid < 16) {
        float s1 = 0.f, s2 = 0.f;
        #pragma unroll
        for (int d = 0; d < DIM; ++d) { float v = ys[tid][d]; s1 += v; s2 += v * v; }
        float mean = s1 * (1.0f / DIM);
        float var  = s2 * (1.0f / DIM) - mean * mean;
        stats[tid][0] = mean;
        stats[tid][1] = rsqrtf(var + 1e-5f);
    }
    __syncthreads();
    for (int e = tid; e < 16*DIM; e += 512) {
        int tt = e / DIM, d = e % DIM;
        x[(size_t)(t0 + tt)*DIM + d] = (ys[tt][d] - stats[tt][0]) * stats[tt][1] * g[d] + be[d];
    }
}

// ---------------------------------------------------------------------------
// Kernel 7: final head
// ---------------------------------------------------------------------------
__global__ __launch_bounds__(64) void wm_final(const float* __restrict__ x,
                                               const int* __restrict__ agent_idx,
                                               const float* __restrict__ aemb,
                                               const float* __restrict__ hw,
                                               const float* __restrict__ hb,
                                               float* __restrict__ out)
{
    __shared__ float hv[DIM];
    const int tid = threadIdx.x;
    const int ai = *agent_idx;
    if (tid < DIM) {
        float s = 0.f;
        for (int r = 0; r < 64; ++r) s += x[(ai*64 + r)*DIM + tid];
        hv[tid] = s * (1.0f / 64.0f);
    }
    __syncthreads();
    if (tid < 16) {
        float a = hb[tid];
        #pragma unroll
        for (int d = 0; d < DIM; ++d) a = fmaf(hv[d], hw[tid*42 + d], a);
        #pragma unroll
        for (int j = 0; j < 8; ++j) a = fmaf(aemb[j], hw[tid*42 + DIM + j], a);
        out[tid] = a;
    }
}

// ---------------------------------------------------------------------------
extern "C" void kernel_launch(void* const* d_in, const int* in_sizes, int n_in,
                              void* d_out, int out_size, void* d_ws, size_t ws_size,
                              hipStream_t stream)
{
    const float* obs    = (const float*)d_in[0];
    const int*   action = (const int*)  d_in[1];
    const float* c1w = (const float*)d_in[2];
    const float* c1b = (const float*)d_in[3];
    const float* c2w = (const float*)d_in[4];
    const float* c2b = (const float*)d_in[5];
    const float* aw  = (const float*)d_in[30];
    const float* ab  = (const float*)d_in[31];
    const float* hw  = (const float*)d_in[32];
    const float* hb  = (const float*)d_in[33];

    float* ws   = (float*)d_ws;
    float* cell = ws;                       // 1024
    float* aemb = ws + 1024;                // 8
    int*   aidx = (int*)(ws + 1040);        // 1
    float* x    = ws + 1056;                // 4096*34
    float* o    = x + SEQ * DIM;            // 4096*34
    u16*   Qb   = (u16*)(o + SEQ * DIM);    // 2*4096*32 bf16
    u16*   Kb   = Qb + 2 * SEQ * 32;        // 2*4096*32 bf16
    u16*   Vc   = Kb + 2 * SEQ * 32;        // 2*128*4*16*8 bf16
    u16*   V16  = Vc + 2 * 128 * 512;       // 2*4096 bf16
    u16*   W1b0 = V16 + 2 * SEQ;            // 131072 u16
    u16*   W2b0 = W1b0 + W1B_ELEMS;         // 98304 u16
    u16*   W1b1 = W2b0 + W2B_ELEMS;
    u16*   W2b1 = W1b1 + W1B_ELEMS;

    wm_wconv<<<2 * (W1B_ELEMS + W2B_ELEMS) / 256, 256, 0, stream>>>(
        (const float*)d_in[10], (const float*)d_in[11], (const float*)d_in[12],
        (const float*)d_in[22], (const float*)d_in[23], (const float*)d_in[24],
        W1b0, W2b0, W1b1, W2b1);
    wm_prep<<<1, 256, 0, stream>>>(obs, action, c1w, c1b, c2w, c2b, aw, ab, cell, aemb, aidx);
    wm_seq<<<16, 256, 0, stream>>>(cell, x);
    for (int l = 0; l < 2; ++l) {
        const int base = 6 + l * 12;
        const float* in_w  = (const float*)d_in[base + 0];
        const float* in_b  = (const float*)d_in[base + 1];
        const float* out_w = (const float*)d_in[base + 2];
        const float* out_b = (const float*)d_in[base + 3];
        const float* ln1g  = (const float*)d_in[base + 8];
        const float* ln1b  = (const float*)d_in[base + 9];
        const float* ln2g  = (const float*)d_in[base + 10];
        const float* ln2b  = (const float*)d_in[base + 11];
        u16* W1b = l ? W1b1 : W1b0;
        u16* W2b = l ? W2b1 : W2b0;

        wm_qkv2<<<162 * (SEQ / 256), 256, 0, stream>>>(x, in_w, in_b, Qb, Kb, Vc, V16);
        wm_attn2<<<dim3(SEQ / 16, NHEAD), 256, 0, stream>>>(Qb, Kb, Vc, V16, o);
        wm_projln<<<SEQ / 4, 256, 0, stream>>>(x, o, out_w, out_b, ln1g, ln1b);
        wm_ff2<<<SEQ / 16, 512, 0, stream>>>(x, W1b, W2b,
            (const float*)d_in[base + 7], ln2g, ln2b);
    }
    wm_final<<<1, 64, 0, stream>>>(x, aidx, aemb, hw, hb, (float*)d_out);
}

// Round 5
// 148.290 us; speedup vs baseline: 4.2528x; 1.2377x over previous
//
#include <hip/hip_runtime.h>
#include <math.h>

// Problem constants
#define SEQ 4096          // N*N tokens
#define DIM 34
#define NHEAD 2
#define HD 17
#define FFDIM 2048
// (1/sqrt(17)) * log2(e): fold softmax scale + exp2 conversion into Q
#define SC2 0.34990494f

#define EXP2F(x) __builtin_amdgcn_exp2f(x)
#define MFMA16(a, b, c) __builtin_amdgcn_mfma_f32_16x16x32_bf16(a, b, c, 0, 0, 0)

typedef unsigned short u16;
typedef __attribute__((ext_vector_type(8))) short bf16x8;
typedef __attribute__((ext_vector_type(4))) float f32x4;

__device__ inline u16 f2bf(float f) {
    uint32_t u = __builtin_bit_cast(uint32_t, f);
    u += 0x7fffu + ((u >> 16) & 1u);
    return (u16)(u >> 16);
}
__device__ inline uint32_t pack2(float a, float b) {
    uint32_t ua = __builtin_bit_cast(uint32_t, a);
    ua += 0x7fffu + ((ua >> 16) & 1u);
    uint32_t ub = __builtin_bit_cast(uint32_t, b);
    ub += 0x7fffu + ((ub >> 16) & 1u);
    return (ua >> 16) | (ub & 0xffff0000u);
}

// ---------------------------------------------------------------------------
// Kernel 1: conv1 -> relu -> conv2 -> relu -> cell[64][16]; agent_idx; a_emb
// 1024 threads; padded LDS so 3x3 loops fully unroll (no branches, no
// serialized LDS-latency chain). Weight indices are wave-uniform -> s_load.
// ---------------------------------------------------------------------------
__global__ __launch_bounds__(1024) void wm_prep(
    const float* __restrict__ obs, const int* __restrict__ action,
    const float* __restrict__ c1w, const float* __restrict__ c1b,
    const float* __restrict__ c2w, const float* __restrict__ c2b,
    const float* __restrict__ aw,  const float* __restrict__ ab,
    float* __restrict__ cell, float* __restrict__ aemb, int* __restrict__ agent_idx)
{
    __shared__ float obsp[2][10][10];
    __shared__ float h1p[16][10][10];
    const int tid = threadIdx.x;
    // zero padding (whole arrays; interiors overwritten below)
    for (int e = tid; e < 200; e += 1024) ((float*)obsp)[e] = 0.f;
    for (int e = tid; e < 1600; e += 1024) ((float*)h1p)[e] = 0.f;
    __syncthreads();
    if (tid < 128) {
        int i = tid >> 6, n = tid & 63, y = n >> 3, xx = n & 7;
        obsp[i][y + 1][xx + 1] = obs[tid];
    }
    __syncthreads();
    // conv1: one thread per output element; o is wave-uniform
    {
        int o = tid >> 6, n = tid & 63, y = n >> 3, xx = n & 7;
        float a = c1b[o];
        #pragma unroll
        for (int i = 0; i < 2; ++i)
            #pragma unroll
            for (int ky = 0; ky < 3; ++ky)
                #pragma unroll
                for (int kx = 0; kx < 3; ++kx)
                    a = fmaf(obsp[i][y + ky][xx + kx], c1w[((o*2 + i)*3 + ky)*3 + kx], a);
        h1p[o][y + 1][xx + 1] = fmaxf(a, 0.f);
    }
    __syncthreads();
    // conv2: fully unrolled 16x3x3
    {
        int o = tid >> 6, n = tid & 63, y = n >> 3, xx = n & 7;
        float a = c2b[o];
        #pragma unroll
        for (int i = 0; i < 16; ++i)
            #pragma unroll
            for (int ky = 0; ky < 3; ++ky)
                #pragma unroll
                for (int kx = 0; kx < 3; ++kx)
                    a = fmaf(h1p[i][y + ky][xx + kx], c2w[((o*16 + i)*3 + ky)*3 + kx], a);
        cell[n*16 + o] = fmaxf(a, 0.f);
    }
    if (tid < 64) {
        float v = obs[tid];
        float mx = v;
        for (int off = 32; off; off >>= 1) mx = fmaxf(mx, __shfl_xor(mx, off));
        unsigned long long mask = __ballot(v == mx);
        if (tid == 0) *agent_idx = (int)(__ffsll(mask) - 1);
    }
    if (tid >= 64 && tid < 72) {
        int k = tid - 64;
        int act = *action;
        aemb[k] = fmaxf(aw[k*4 + act] + ab[k], 0.f);
    }
}

// ---------------------------------------------------------------------------
// Kernel 2: build seq [4096][34]
// ---------------------------------------------------------------------------
__global__ __launch_bounds__(256) void wm_seq(const float* __restrict__ cell,
                                              float* __restrict__ x)
{
    __shared__ float cs[64][16];
    const int tid = threadIdx.x;
    for (int e = tid; e < 1024; e += 256) cs[e >> 4][e & 15] = cell[e];
    __syncthreads();
    const int t0 = blockIdx.x * 256;
    for (int e = tid; e < 256 * DIM; e += 256) {
        int t = t0 + e / DIM, d = e % DIM;
        int i = t >> 6, j = t & 63;
        float v;
        if (d < 16)       v = cs[i][d];
        else if (d < 32)  v = cs[j][d - 16];
        else if (d == 32) v = (float)((i >> 3) - (j >> 3)) * (1.0f / 3.5f);
        else              v = (float)((i & 7) - (j & 7)) * (1.0f / 3.5f);
        x[t0 * DIM + e] = v;
    }
}

// ---------------------------------------------------------------------------
// Kernel 2b: repack FFN weights to bf16, both layers.
//  W1b[2048][64]: cols 0..33 = w1[n][k], col 34 = b1[n], rest 0
//  W2b[48][2048]: rows 0..33 = w2[n][k], rest 0
// ---------------------------------------------------------------------------
#define W1B_ELEMS (FFDIM * 64)       // 131072
#define W2B_ELEMS (48 * FFDIM)       // 98304
__global__ __launch_bounds__(256) void wm_wconv(
    const float* __restrict__ w1a, const float* __restrict__ b1a, const float* __restrict__ w2a,
    const float* __restrict__ w1b, const float* __restrict__ b1b, const float* __restrict__ w2b,
    u16* __restrict__ W1A, u16* __restrict__ W2A,
    u16* __restrict__ W1B, u16* __restrict__ W2B)
{
    int id = blockIdx.x * 256 + threadIdx.x;
    const int half = W1B_ELEMS + W2B_ELEMS;
    const float* w1 = w1a; const float* b1 = b1a; const float* w2 = w2a;
    u16* W1 = W1A; u16* W2 = W2A;
    if (id >= half) { id -= half; w1 = w1b; b1 = b1b; w2 = w2b; W1 = W1B; W2 = W2B; }
    if (id < W1B_ELEMS) {
        int n = id >> 6, c = id & 63;
        float v = (c < DIM) ? w1[n*DIM + c] : ((c == DIM) ? b1[n] : 0.f);
        W1[id] = f2bf(v);
    } else {
        int e = id - W1B_ELEMS;
        int n = e >> 11;
        float v = (n < DIM) ? w2[(n << 11) + (e & 2047)] : 0.f;
        W2[e] = f2bf(v);
    }
}

// ---------------------------------------------------------------------------
// Kernel 3: qkv projection -> MFMA-ready bf16 layouts.
// ---------------------------------------------------------------------------
__global__ __launch_bounds__(256) void wm_qkv2(const float* __restrict__ x,
        const float* __restrict__ w, const float* __restrict__ b,
        u16* __restrict__ Qb, u16* __restrict__ Kb,
        u16* __restrict__ Vc, u16* __restrict__ V16)
{
    int gid = blockIdx.x * 256 + threadIdx.x;
    int t = gid & (SEQ - 1);
    int slot = gid >> 12;
    if (slot < 128) {
        int isK = slot >> 6;
        int hs  = slot & 31;
        int h   = (slot >> 5) & 1;
        float val = 0.f;
        if (hs < HD) {
            int row = isK*DIM + h*HD + hs;
            const float* wr = w + row*DIM;
            const float* xr = x + t*DIM;
            float a = b[row];
            #pragma unroll
            for (int d = 0; d < DIM; ++d) a = fmaf(xr[d], wr[d], a);
            val = isK ? a : a * SC2;
        }
        u16* dst = isK ? Kb : Qb;
        dst[(((size_t)h*SEQ + t) << 5) + hs] = f2bf(val);
    } else {
        int s = slot - 128;
        int h = s / HD, dd = s % HD;
        int row = 2*DIM + h*HD + dd;
        const float* wr = w + row*DIM;
        const float* xr = x + t*DIM;
        float a = b[row];
        #pragma unroll
        for (int d = 0; d < DIM; ++d) a = fmaf(xr[d], wr[d], a);
        u16 v = f2bf(a);
        if (dd == 16) V16[h*SEQ + t] = v;
        else {
            int c = t >> 5, g = (t >> 3) & 3, i = t & 7;
            Vc[((((size_t)h*128 + c)*4 + g)*16 + dd)*8 + i] = v;
        }
    }
}

// ---------------------------------------------------------------------------
// Kernel 4: MFMA flash attention (unchanged).
// ---------------------------------------------------------------------------
__global__ __launch_bounds__(256) void wm_attn2(const u16* __restrict__ Qb,
        const u16* __restrict__ Kb, const u16* __restrict__ Vc,
        const u16* __restrict__ V16, float* __restrict__ o)
{
    const int qt = blockIdx.x, h = blockIdx.y;
    const int tid = threadIdx.x;
    const int wv = tid >> 6, l = tid & 63;
    const int q = l & 15, g = l >> 4;

    __shared__ float red[3][64][8];

    const u16* Qh = Qb + (((size_t)h*SEQ + qt*16 + q) << 5) + 8*g;
    const u16* Kh = Kb + ((size_t)h*SEQ << 5);
    const u16* Vh = Vc + (size_t)h*128*512;
    const u16* V6 = V16 + (size_t)h*SEQ;

    const bf16x8 qf = *(const bf16x8*)Qh;
    const f32x4 zero4 = {0.f, 0.f, 0.f, 0.f};

    f32x4 olo = zero4, ohi = zero4;
    float m = -INFINITY, lsum = 0.f;

    for (int c = wv*32; c < wv*32 + 32; ++c) {
        const int k0 = c * 32;
        bf16x8 kf0 = *(const bf16x8*)(Kh + ((size_t)(k0 + q) << 5) + 8*g);
        bf16x8 kf1 = *(const bf16x8*)(Kh + ((size_t)(k0 + 16 + q) << 5) + 8*g);
        f32x4 s0 = MFMA16(kf0, qf, zero4);
        f32x4 s1 = MFMA16(kf1, qf, zero4);
        float tm = fmaxf(fmaxf(fmaxf(s0[0], s0[1]), fmaxf(s0[2], s0[3])),
                         fmaxf(fmaxf(s1[0], s1[1]), fmaxf(s1[2], s1[3])));
        tm = fmaxf(tm, __shfl_xor(tm, 16));
        tm = fmaxf(tm, __shfl_xor(tm, 32));
        float newm = fmaxf(m, tm);
        float fac = EXP2F(m - newm);
        m = newm;
        float p00 = EXP2F(s0[0] - m), p01 = EXP2F(s0[1] - m);
        float p02 = EXP2F(s0[2] - m), p03 = EXP2F(s0[3] - m);
        float p10 = EXP2F(s1[0] - m), p11 = EXP2F(s1[1] - m);
        float p12 = EXP2F(s1[2] - m), p13 = EXP2F(s1[3] - m);
        float ts = ((p00 + p01) + (p02 + p03)) + ((p10 + p11) + (p12 + p13));
        ts += __shfl_xor(ts, 16);
        ts += __shfl_xor(ts, 32);
        lsum = lsum * fac + ts;
        olo[0] *= fac; olo[1] *= fac; olo[2] *= fac; olo[3] *= fac;
        ohi[0] *= fac; ohi[1] *= fac; ohi[2] *= fac; ohi[3] *= fac;
        uint32_t a0t0 = pack2(p00, p01), a1t0 = pack2(p02, p03);
        uint32_t a0t1 = pack2(p10, p11), a1t1 = pack2(p12, p13);
        int srcA = q + 32*(g & 1);
        int srcB = srcA + 16;
        uint32_t w0a = (uint32_t)__shfl((int)a0t0, srcA), w0b = (uint32_t)__shfl((int)a0t1, srcA);
        uint32_t w1a = (uint32_t)__shfl((int)a1t0, srcA), w1b = (uint32_t)__shfl((int)a1t1, srcA);
        uint32_t w2a = (uint32_t)__shfl((int)a0t0, srcB), w2b = (uint32_t)__shfl((int)a0t1, srcB);
        uint32_t w3a = (uint32_t)__shfl((int)a1t0, srcB), w3b = (uint32_t)__shfl((int)a1t1, srcB);
        const bool hi = (g >= 2);
        union { uint32_t u[4]; bf16x8 v; } pu;
        pu.u[0] = hi ? w0b : w0a;
        pu.u[1] = hi ? w1b : w1a;
        pu.u[2] = hi ? w2b : w2a;
        pu.u[3] = hi ? w3b : w3a;
        bf16x8 pf = pu.v;
        bf16x8 vf = *(const bf16x8*)(Vh + (size_t)(c*4 + g)*128 + q*8);
        bf16x8 v6 = {};
        if (q == 0) v6 = *(const bf16x8*)(V6 + k0 + 8*g);
        olo = MFMA16(vf, pf, olo);
        ohi = MFMA16(v6, pf, ohi);
    }

    if (wv) {
        float* r = red[wv - 1][l];
        r[0] = m; r[1] = lsum;
        r[2] = olo[0]; r[3] = olo[1]; r[4] = olo[2]; r[5] = olo[3];
        r[6] = ohi[0];
    }
    __syncthreads();
    if (wv == 0) {
        float M = m;
        #pragma unroll
        for (int p = 0; p < 3; ++p) M = fmaxf(M, red[p][l][0]);
        float f = EXP2F(m - M);
        float lt = lsum * f;
        float o0 = olo[0]*f, o1 = olo[1]*f, o2 = olo[2]*f, o3 = olo[3]*f, o6 = ohi[0]*f;
        #pragma unroll
        for (int p = 0; p < 3; ++p) {
            float* r = red[p][l];
            float fp = EXP2F(r[0] - M);
            lt += r[1] * fp;
            o0 += r[2]*fp; o1 += r[3]*fp; o2 += r[4]*fp; o3 += r[5]*fp; o6 += r[6]*fp;
        }
        float inv = 1.f / lt;
        float* orow = o + (size_t)(qt*16 + q)*DIM + h*HD;
        orow[4*g + 0] = o0*inv; orow[4*g + 1] = o1*inv;
        orow[4*g + 2] = o2*inv; orow[4*g + 3] = o3*inv;
        if (g == 0) orow[16] = o6*inv;
    }
}

// ---------------------------------------------------------------------------
// Kernel 5: x = LN(x + o @ out_w.T + out_b). One wave per token.
// ---------------------------------------------------------------------------
__global__ __launch_bounds__(256) void wm_projln(float* __restrict__ x,
                                                 const float* __restrict__ o,
                                                 const float* __restrict__ w,
                                                 const float* __restrict__ b,
                                                 const float* __restrict__ g,
                                                 const float* __restrict__ be)
{
    const int wv = threadIdx.x >> 6, lane = threadIdx.x & 63;
    const int t = blockIdx.x * 4 + wv;
    const float* orow = o + t * DIM;
    float r = 0.f;
    if (lane < DIM) {
        float accv = b[lane];
        const float* wr = w + lane * DIM;
        #pragma unroll
        for (int e = 0; e < DIM; ++e) accv = fmaf(orow[e], wr[e], accv);
        r = x[t*DIM + lane] + accv;
    }
    float s1 = r, s2 = r * r;
    for (int off = 32; off; off >>= 1) { s1 += __shfl_xor(s1, off); s2 += __shfl_xor(s2, off); }
    float mean = s1 * (1.0f / DIM);
    float var  = s2 * (1.0f / DIM) - mean * mean;
    float rstd = rsqrtf(var + 1e-5f);
    if (lane < DIM) x[t*DIM + lane] = (r - mean) * rstd * g[lane] + be[lane];
}

// ---------------------------------------------------------------------------
// Kernel 6: MFMA fused FFN + residual + LN2, in-place on x. (unchanged)
// ---------------------------------------------------------------------------
__global__ __launch_bounds__(512) void wm_ff2(float* __restrict__ x,
        const u16* __restrict__ W1b, const u16* __restrict__ W2b,
        const float* __restrict__ b2, const float* __restrict__ g,
        const float* __restrict__ be)
{
    __shared__ u16 Hs[8][16][128];       // 32 KB, wave-private [16][128], XOR-swizzled
    __shared__ float red[8][16][52];     // 26.6 KB
    __shared__ float ys[16][DIM];
    __shared__ float stats[16][2];
    const int tid = threadIdx.x, wv = tid >> 6, l = tid & 63;
    const int q = l & 15, g4 = l >> 4;
    const int t0 = blockIdx.x * 16;

    const float* xr = x + (size_t)(t0 + q) * DIM;
    union { uint32_t u[4]; bf16x8 v; } a0, a1;
    #pragma unroll
    for (int j = 0; j < 4; ++j)
        a0.u[j] = pack2(xr[g4*8 + 2*j], xr[g4*8 + 2*j + 1]);
    a1.u[0] = 0; a1.u[1] = 0; a1.u[2] = 0; a1.u[3] = 0;
    if (g4 == 0) {
        a1.u[0] = pack2(xr[32], xr[33]);
        a1.u[1] = pack2(1.0f, 0.f);      // col 34 = bias slot
    }
    const f32x4 zero4 = {0.f, 0.f, 0.f, 0.f};

    f32x4 acc0 = zero4, acc1 = zero4, acc2 = zero4;
    for (int ph = 0; ph < 2; ++ph) {
        const int hb = wv*256 + ph*128;
        #pragma unroll
        for (int nt = 0; nt < 8; ++nt) {
            const u16* brow = W1b + (size_t)(hb + nt*16 + q) * 64 + g4*8;
            bf16x8 b0 = *(const bf16x8*)brow;
            bf16x8 b1f = *(const bf16x8*)(brow + 32);
            f32x4 c = MFMA16(a0.v, b0, zero4);
            c = MFMA16(a1.v, b1f, c);
            #pragma unroll
            for (int r = 0; r < 4; ++r) {
                int m = 4*g4 + r;
                int byte = ((nt*16 + q) * 2) ^ ((m & 7) << 4);
                *(u16*)((char*)&Hs[wv][m][0] + byte) = f2bf(fmaxf(c[r], 0.f));
            }
        }
        __syncthreads();
        #pragma unroll
        for (int ks = 0; ks < 4; ++ks) {
            int byte = (ks*64 + g4*16) ^ ((q & 7) << 4);
            bf16x8 af = *(const bf16x8*)((char*)&Hs[wv][q][0] + byte);
            const u16* bp = W2b + (size_t)q * FFDIM + hb + ks*32 + g4*8;
            acc0 = MFMA16(af, *(const bf16x8*)bp, acc0);
            acc1 = MFMA16(af, *(const bf16x8*)(bp + 16*FFDIM), acc1);
            acc2 = MFMA16(af, *(const bf16x8*)(bp + 32*FFDIM), acc2);
        }
        __syncthreads();
    }
    #pragma unroll
    for (int r = 0; r < 4; ++r) {
        red[wv][4*g4 + r][q]      = acc0[r];
        red[wv][4*g4 + r][16 + q] = acc1[r];
        red[wv][4*g4 + r][32 + q] = acc2[r];
    }
    __syncthreads();
    for (int e = tid; e < 16*DIM; e += 512) {
        int tt = e / DIM, d = e % DIM;
        float v = x[(size_t)(t0 + tt)*DIM + d] + b2[d];
        #pragma unroll
        for (int w = 0; w < 8; ++w) v += red[w][tt][d];
        ys[tt][d] = v;
    }
    __syncthreads();
    if (tid < 16) {
        float s1 = 0.f, s2 = 0.f;
        #pragma unroll
        for (int d = 0; d < DIM; ++d) { float v = ys[tid][d]; s1 += v; s2 += v * v; }
        float mean = s1 * (1.0f / DIM);
        float var  = s2 * (1.0f / DIM) - mean * mean;
        stats[tid][0] = mean;
        stats[tid][1] = rsqrtf(var + 1e-5f);
    }
    __syncthreads();
    for (int e = tid; e < 16*DIM; e += 512) {
        int tt = e / DIM, d = e % DIM;
        x[(size_t)(t0 + tt)*DIM + d] = (ys[tt][d] - stats[tt][0]) * stats[tt][1] * g[d] + be[d];
    }
}

// ---------------------------------------------------------------------------
// Kernel 7: final head
// ---------------------------------------------------------------------------
__global__ __launch_bounds__(64) void wm_final(const float* __restrict__ x,
                                               const int* __restrict__ agent_idx,
                                               const float* __restrict__ aemb,
                                               const float* __restrict__ hw,
                                               const float* __restrict__ hb,
                                               float* __restrict__ out)
{
    __shared__ float hv[DIM];
    const int tid = threadIdx.x;
    const int ai = *agent_idx;
    if (tid < DIM) {
        float s = 0.f;
        for (int r = 0; r < 64; ++r) s += x[(ai*64 + r)*DIM + tid];
        hv[tid] = s * (1.0f / 64.0f);
    }
    __syncthreads();
    if (tid < 16) {
        float a = hb[tid];
        #pragma unroll
        for (int d = 0; d < DIM; ++d) a = fmaf(hv[d], hw[tid*42 + d], a);
        #pragma unroll
        for (int j = 0; j < 8; ++j) a = fmaf(aemb[j], hw[tid*42 + DIM + j], a);
        out[tid] = a;
    }
}

// ---------------------------------------------------------------------------
extern "C" void kernel_launch(void* const* d_in, const int* in_sizes, int n_in,
                              void* d_out, int out_size, void* d_ws, size_t ws_size,
                              hipStream_t stream)
{
    const float* obs    = (const float*)d_in[0];
    const int*   action = (const int*)  d_in[1];
    const float* c1w = (const float*)d_in[2];
    const float* c1b = (const float*)d_in[3];
    const float* c2w = (const float*)d_in[4];
    const float* c2b = (const float*)d_in[5];
    const float* aw  = (const float*)d_in[30];
    const float* ab  = (const float*)d_in[31];
    const float* hw  = (const float*)d_in[32];
    const float* hb  = (const float*)d_in[33];

    float* ws   = (float*)d_ws;
    float* cell = ws;                       // 1024
    float* aemb = ws + 1024;                // 8
    int*   aidx = (int*)(ws + 1040);        // 1
    float* x    = ws + 1056;                // 4096*34
    float* o    = x + SEQ * DIM;            // 4096*34
    u16*   Qb   = (u16*)(o + SEQ * DIM);    // 2*4096*32 bf16
    u16*   Kb   = Qb + 2 * SEQ * 32;        // 2*4096*32 bf16
    u16*   Vc   = Kb + 2 * SEQ * 32;        // 2*128*4*16*8 bf16
    u16*   V16  = Vc + 2 * 128 * 512;       // 2*4096 bf16
    u16*   W1b0 = V16 + 2 * SEQ;            // 131072 u16
    u16*   W2b0 = W1b0 + W1B_ELEMS;         // 98304 u16
    u16*   W1b1 = W2b0 + W2B_ELEMS;
    u16*   W2b1 = W1b1 + W1B_ELEMS;

    wm_wconv<<<2 * (W1B_ELEMS + W2B_ELEMS) / 256, 256, 0, stream>>>(
        (const float*)d_in[10], (const float*)d_in[11], (const float*)d_in[12],
        (const float*)d_in[22], (const float*)d_in[23], (const float*)d_in[24],
        W1b0, W2b0, W1b1, W2b1);
    wm_prep<<<1, 1024, 0, stream>>>(obs, action, c1w, c1b, c2w, c2b, aw, ab, cell, aemb, aidx);
    wm_seq<<<16, 256, 0, stream>>>(cell, x);
    for (int l = 0; l < 2; ++l) {
        const int base = 6 + l * 12;
        const float* in_w  = (const float*)d_in[base + 0];
        const float* in_b  = (const float*)d_in[base + 1];
        const float* out_w = (const float*)d_in[base + 2];
        const float* out_b = (const float*)d_in[base + 3];
        const float* ln1g  = (const float*)d_in[base + 8];
        const float* ln1b  = (const float*)d_in[base + 9];
        const float* ln2g  = (const float*)d_in[base + 10];
        const float* ln2b  = (const float*)d_in[base + 11];
        u16* W1b = l ? W1b1 : W1b0;
        u16* W2b = l ? W2b1 : W2b0;

        wm_qkv2<<<162 * (SEQ / 256), 256, 0, stream>>>(x, in_w, in_b, Qb, Kb, Vc, V16);
        wm_attn2<<<dim3(SEQ / 16, NHEAD), 256, 0, stream>>>(Qb, Kb, Vc, V16, o);
        wm_projln<<<SEQ / 4, 256, 0, stream>>>(x, o, out_w, out_b, ln1g, ln1b);
        wm_ff2<<<SEQ / 16, 512, 0, stream>>>(x, W1b, W2b,
            (const float*)d_in[base + 7], ln2g, ln2b);
    }
    wm_final<<<1, 64, 0, stream>>>(x, aidx, aemb, hw, hb, (float*)d_out);
}

// Round 6
// 124.499 us; speedup vs baseline: 5.0655x; 1.1911x over previous
//
#include <hip/hip_runtime.h>
#include <math.h>

// Problem constants
#define SEQ 4096          // N*N tokens
#define DIM 34
#define NHEAD 2
#define HD 17
#define FFDIM 2048
// (1/sqrt(17)) * log2(e): fold softmax scale + exp2 conversion into Q
#define SC2 0.34990494f

#define EXP2F(x) __builtin_amdgcn_exp2f(x)
#define MFMA16(a, b, c) __builtin_amdgcn_mfma_f32_16x16x32_bf16(a, b, c, 0, 0, 0)

typedef unsigned short u16;
typedef __attribute__((ext_vector_type(8))) short bf16x8;
typedef __attribute__((ext_vector_type(4))) float f32x4;

__device__ inline u16 f2bf(float f) {
    uint32_t u = __builtin_bit_cast(uint32_t, f);
    u += 0x7fffu + ((u >> 16) & 1u);
    return (u16)(u >> 16);
}
__device__ inline uint32_t pack2(float a, float b) {
    uint32_t ua = __builtin_bit_cast(uint32_t, a);
    ua += 0x7fffu + ((ua >> 16) & 1u);
    uint32_t ub = __builtin_bit_cast(uint32_t, b);
    ub += 0x7fffu + ((ub >> 16) & 1u);
    return (ua >> 16) | (ub & 0xffff0000u);
}

#define W1B_ELEMS (FFDIM * 64)       // 131072
#define W2B_ELEMS (48 * FFDIM)       // 98304
#define NWCONV 448                   // 2*(W1B+W2B)/1024 blocks of repack work

// ---------------------------------------------------------------------------
// Kernel 1: wm_pre — block-partitioned:
//  blocks [0,448): repack FFN weights (both layers) to bf16 MFMA layouts
//  blocks [448,512): redundant conv1+conv2 in LDS, then emit x rows and
//                    layer-0 Q/K/V in MFMA-ready bf16 layouts (64 tokens/blk)
//  Qb/Kb[h][t][32] (pads 17..31 zeroed here), Vc PV-fragment layout, V16.
// ---------------------------------------------------------------------------
__global__ __launch_bounds__(1024) void wm_pre(
    const float* __restrict__ obs,
    const float* __restrict__ c1w, const float* __restrict__ c1b,
    const float* __restrict__ c2w, const float* __restrict__ c2b,
    const float* __restrict__ in_w, const float* __restrict__ in_b,   // layer 0
    const float* __restrict__ w1a, const float* __restrict__ b1a, const float* __restrict__ w2a,
    const float* __restrict__ w1b, const float* __restrict__ b1b, const float* __restrict__ w2b,
    float* __restrict__ x, u16* __restrict__ Qb, u16* __restrict__ Kb,
    u16* __restrict__ Vc, u16* __restrict__ V16,
    u16* __restrict__ W1A, u16* __restrict__ W2A,
    u16* __restrict__ W1B, u16* __restrict__ W2B)
{
    const int tid = threadIdx.x;
    if (blockIdx.x < NWCONV) {
        // ---- weight repack ----
        int id = blockIdx.x * 1024 + tid;
        const int half = W1B_ELEMS + W2B_ELEMS;
        const float* w1 = w1a; const float* b1 = b1a; const float* w2 = w2a;
        u16* W1 = W1A; u16* W2 = W2A;
        if (id >= half) { id -= half; w1 = w1b; b1 = b1b; w2 = w2b; W1 = W1B; W2 = W2B; }
        if (id < W1B_ELEMS) {
            int n = id >> 6, c = id & 63;
            float v = (c < DIM) ? w1[n*DIM + c] : ((c == DIM) ? b1[n] : 0.f);
            W1[id] = f2bf(v);
        } else {
            int e = id - W1B_ELEMS;
            int n = e >> 11;
            float v = (n < DIM) ? w2[(n << 11) + (e & 2047)] : 0.f;
            W2[e] = f2bf(v);
        }
        return;
    }
    // ---- conv + seq + qkv(layer 0) for 64 tokens ----
    __shared__ float obsp[2][10][10];
    __shared__ float h1p[16][10][10];
    __shared__ float cs[64][16];
    const int sb = blockIdx.x - NWCONV;       // 0..63
    const int t0 = sb * 64;

    for (int e = tid; e < 200; e += 1024) ((float*)obsp)[e] = 0.f;
    for (int e = tid; e < 1600; e += 1024) ((float*)h1p)[e] = 0.f;
    __syncthreads();
    if (tid < 128) {
        int i = tid >> 6, n = tid & 63, y = n >> 3, xx = n & 7;
        obsp[i][y + 1][xx + 1] = obs[tid];
    }
    __syncthreads();
    {   // conv1
        int o = tid >> 6, n = tid & 63, y = n >> 3, xx = n & 7;
        float a = c1b[o];
        #pragma unroll
        for (int i = 0; i < 2; ++i)
            #pragma unroll
            for (int ky = 0; ky < 3; ++ky)
                #pragma unroll
                for (int kx = 0; kx < 3; ++kx)
                    a = fmaf(obsp[i][y + ky][xx + kx], c1w[((o*2 + i)*3 + ky)*3 + kx], a);
        h1p[o][y + 1][xx + 1] = fmaxf(a, 0.f);
    }
    __syncthreads();
    {   // conv2 -> cs[n][o]
        int o = tid >> 6, n = tid & 63, y = n >> 3, xx = n & 7;
        float a = c2b[o];
        #pragma unroll
        for (int i = 0; i < 16; ++i)
            #pragma unroll
            for (int ky = 0; ky < 3; ++ky)
                #pragma unroll
                for (int kx = 0; kx < 3; ++kx)
                    a = fmaf(h1p[i][y + ky][xx + kx], c2w[((o*16 + i)*3 + ky)*3 + kx], a);
        cs[n][o] = fmaxf(a, 0.f);
    }
    __syncthreads();
    // emit x rows for tokens t0..t0+63
    for (int e = tid; e < 64 * DIM; e += 1024) {
        int tl = e / DIM, d = e % DIM;
        int t = t0 + tl, i = t >> 6, j = t & 63;
        float v;
        if (d < 16)       v = cs[i][d];
        else if (d < 32)  v = cs[j][d - 16];
        else if (d == 32) v = (float)((i >> 3) - (j >> 3)) * (1.0f / 3.5f);
        else              v = (float)((i & 7) - (j & 7)) * (1.0f / 3.5f);
        x[t0 * DIM + e] = v;
    }
    // emit layer-0 qkv: slot map identical to old wm_qkv2 (slot wave-uniform)
    for (int ii = 0; ii < 11; ++ii) {
        int e = tid + ii * 1024;
        if (e >= 64 * 162) break;
        int t = t0 + (e & 63), slot = e >> 6;
        int i = t >> 6, j = t & 63;
        float dx = (float)((i >> 3) - (j >> 3)) * (1.0f / 3.5f);
        float dy = (float)((i & 7) - (j & 7)) * (1.0f / 3.5f);
        if (slot < 128) {
            int isK = slot >> 6, h2 = (slot >> 5) & 1, hs = slot & 31;
            float val = 0.f;
            if (hs < HD) {
                int row = isK*DIM + h2*HD + hs;
                const float* wr = in_w + row*DIM;
                float a = in_b[row];
                #pragma unroll
                for (int d = 0; d < 16; ++d) a = fmaf(cs[i][d], wr[d], a);
                #pragma unroll
                for (int d = 0; d < 16; ++d) a = fmaf(cs[j][d], wr[16 + d], a);
                a = fmaf(dx, wr[32], a);
                a = fmaf(dy, wr[33], a);
                val = isK ? a : a * SC2;
            }
            u16* dst = isK ? Kb : Qb;
            dst[(((size_t)h2*SEQ + t) << 5) + hs] = f2bf(val);
        } else {
            int s = slot - 128;
            int h2 = s >= HD, dd = s - h2*HD;
            int row = 2*DIM + h2*HD + dd;
            const float* wr = in_w + row*DIM;
            float a = in_b[row];
            #pragma unroll
            for (int d = 0; d < 16; ++d) a = fmaf(cs[i][d], wr[d], a);
            #pragma unroll
            for (int d = 0; d < 16; ++d) a = fmaf(cs[j][d], wr[16 + d], a);
            a = fmaf(dx, wr[32], a);
            a = fmaf(dy, wr[33], a);
            u16 v = f2bf(a);
            if (dd == 16) V16[h2*SEQ + t] = v;
            else {
                int c = t >> 5, g = (t >> 3) & 3, ix = t & 7;
                Vc[((((size_t)h2*128 + c)*4 + g)*16 + dd)*8 + ix] = v;
            }
        }
    }
}

// ---------------------------------------------------------------------------
// Kernel 2: MFMA flash attention + out-proj + residual + LN1, in-place on x.
// 512 thr = 8 waves: wave wv -> head wv>>2, key range (wv&3)*1024..+1024.
// Cross-wave combine in LDS, then projln epilogue for the block's 16 tokens.
// ---------------------------------------------------------------------------
__global__ __launch_bounds__(512) void wm_attn3(const u16* __restrict__ Qb,
        const u16* __restrict__ Kb, const u16* __restrict__ Vc,
        const u16* __restrict__ V16, float* __restrict__ x,
        const float* __restrict__ ow, const float* __restrict__ obias,
        const float* __restrict__ g, const float* __restrict__ be)
{
    const int qt = blockIdx.x;
    const int tid = threadIdx.x;
    const int wv = tid >> 6, l = tid & 63;
    const int h = wv >> 2, rr = wv & 3;
    const int q = l & 15, gg = l >> 4;

    __shared__ float red[8][64][9];
    __shared__ float os[16][DIM];
    __shared__ float ys[16][DIM];
    __shared__ float stats[16][2];

    const u16* Qh = Qb + (((size_t)h*SEQ + qt*16 + q) << 5) + 8*gg;
    const u16* Kh = Kb + ((size_t)h*SEQ << 5);
    const u16* Vh = Vc + (size_t)h*128*512;
    const u16* V6 = V16 + (size_t)h*SEQ;

    const bf16x8 qf = *(const bf16x8*)Qh;
    const f32x4 zero4 = {0.f, 0.f, 0.f, 0.f};

    f32x4 olo = zero4, ohi = zero4;
    float m = -INFINITY, lsum = 0.f;

    for (int c = rr*32; c < rr*32 + 32; ++c) {
        const int k0 = c * 32;
        bf16x8 kf0 = *(const bf16x8*)(Kh + ((size_t)(k0 + q) << 5) + 8*gg);
        bf16x8 kf1 = *(const bf16x8*)(Kh + ((size_t)(k0 + 16 + q) << 5) + 8*gg);
        f32x4 s0 = MFMA16(kf0, qf, zero4);
        f32x4 s1 = MFMA16(kf1, qf, zero4);
        float tm = fmaxf(fmaxf(fmaxf(s0[0], s0[1]), fmaxf(s0[2], s0[3])),
                         fmaxf(fmaxf(s1[0], s1[1]), fmaxf(s1[2], s1[3])));
        tm = fmaxf(tm, __shfl_xor(tm, 16));
        tm = fmaxf(tm, __shfl_xor(tm, 32));
        float newm = fmaxf(m, tm);
        float fac = EXP2F(m - newm);
        m = newm;
        float p00 = EXP2F(s0[0] - m), p01 = EXP2F(s0[1] - m);
        float p02 = EXP2F(s0[2] - m), p03 = EXP2F(s0[3] - m);
        float p10 = EXP2F(s1[0] - m), p11 = EXP2F(s1[1] - m);
        float p12 = EXP2F(s1[2] - m), p13 = EXP2F(s1[3] - m);
        float ts = ((p00 + p01) + (p02 + p03)) + ((p10 + p11) + (p12 + p13));
        ts += __shfl_xor(ts, 16);
        ts += __shfl_xor(ts, 32);
        lsum = lsum * fac + ts;
        olo[0] *= fac; olo[1] *= fac; olo[2] *= fac; olo[3] *= fac;
        ohi[0] *= fac; ohi[1] *= fac; ohi[2] *= fac; ohi[3] *= fac;
        uint32_t a0t0 = pack2(p00, p01), a1t0 = pack2(p02, p03);
        uint32_t a0t1 = pack2(p10, p11), a1t1 = pack2(p12, p13);
        int srcA = q + 32*(gg & 1);
        int srcB = srcA + 16;
        uint32_t w0a = (uint32_t)__shfl((int)a0t0, srcA), w0b = (uint32_t)__shfl((int)a0t1, srcA);
        uint32_t w1a = (uint32_t)__shfl((int)a1t0, srcA), w1b = (uint32_t)__shfl((int)a1t1, srcA);
        uint32_t w2a = (uint32_t)__shfl((int)a0t0, srcB), w2b = (uint32_t)__shfl((int)a0t1, srcB);
        uint32_t w3a = (uint32_t)__shfl((int)a1t0, srcB), w3b = (uint32_t)__shfl((int)a1t1, srcB);
        const bool hi = (gg >= 2);
        union { uint32_t u[4]; bf16x8 v; } pu;
        pu.u[0] = hi ? w0b : w0a;
        pu.u[1] = hi ? w1b : w1a;
        pu.u[2] = hi ? w2b : w2a;
        pu.u[3] = hi ? w3b : w3a;
        bf16x8 pf = pu.v;
        bf16x8 vf = *(const bf16x8*)(Vh + (size_t)(c*4 + gg)*128 + q*8);
        bf16x8 v6 = {};
        if (q == 0) v6 = *(const bf16x8*)(V6 + k0 + 8*gg);
        olo = MFMA16(vf, pf, olo);
        ohi = MFMA16(v6, pf, ohi);
    }

    {
        float* r = red[wv][l];
        r[0] = m; r[1] = lsum;
        r[2] = olo[0]; r[3] = olo[1]; r[4] = olo[2]; r[5] = olo[3];
        r[6] = ohi[0];
    }
    __syncthreads();
    if (rr == 0) {
        float M = red[wv][l][0];
        #pragma unroll
        for (int p = 1; p < 4; ++p) M = fmaxf(M, red[wv + p][l][0]);
        float lt = 0.f, o0 = 0.f, o1 = 0.f, o2 = 0.f, o3 = 0.f, o6 = 0.f;
        #pragma unroll
        for (int p = 0; p < 4; ++p) {
            float* r = red[wv + p][l];
            float fp = EXP2F(r[0] - M);
            lt += r[1]*fp;
            o0 += r[2]*fp; o1 += r[3]*fp; o2 += r[4]*fp; o3 += r[5]*fp; o6 += r[6]*fp;
        }
        float inv = 1.f / lt;
        os[q][h*HD + 4*gg + 0] = o0*inv;
        os[q][h*HD + 4*gg + 1] = o1*inv;
        os[q][h*HD + 4*gg + 2] = o2*inv;
        os[q][h*HD + 4*gg + 3] = o3*inv;
        if (gg == 0) os[q][h*HD + 16] = o6*inv;
    }
    __syncthreads();
    // out-proj + residual
    for (int e = tid; e < 16 * DIM; e += 512) {
        int tt = e / DIM, d = e % DIM;
        const float* wr = ow + d*DIM;
        float acc = obias[d];
        #pragma unroll
        for (int k = 0; k < DIM; ++k) acc = fmaf(os[tt][k], wr[k], acc);
        ys[tt][d] = x[(size_t)(qt*16 + tt)*DIM + d] + acc;
    }
    __syncthreads();
    if (tid < 16) {
        float s1 = 0.f, s2 = 0.f;
        #pragma unroll
        for (int d = 0; d < DIM; ++d) { float v = ys[tid][d]; s1 += v; s2 += v*v; }
        float mean = s1 * (1.0f / DIM);
        float var  = s2 * (1.0f / DIM) - mean*mean;
        stats[tid][0] = mean;
        stats[tid][1] = rsqrtf(var + 1e-5f);
    }
    __syncthreads();
    for (int e = tid; e < 16 * DIM; e += 512) {
        int tt = e / DIM, d = e % DIM;
        x[(size_t)(qt*16 + tt)*DIM + d] = (ys[tt][d] - stats[tt][0]) * stats[tt][1] * g[d] + be[d];
    }
}

// ---------------------------------------------------------------------------
// Kernel 3: MFMA fused FFN + residual + LN2 (+ optional next-layer QKV emit).
// ---------------------------------------------------------------------------
__global__ __launch_bounds__(512) void wm_ff3(float* __restrict__ x,
        const u16* __restrict__ W1b, const u16* __restrict__ W2b,
        const float* __restrict__ b2, const float* __restrict__ g,
        const float* __restrict__ be,
        const float* __restrict__ in_w, const float* __restrict__ in_b,
        u16* __restrict__ Qb, u16* __restrict__ Kb,
        u16* __restrict__ Vc, u16* __restrict__ V16, int do_qkv)
{
    __shared__ u16 Hs[8][16][128];       // 32 KB, wave-private, XOR-swizzled
    __shared__ float red[8][16][52];     // 26.6 KB
    __shared__ float ys[16][DIM];
    __shared__ float stats[16][2];
    const int tid = threadIdx.x, wv = tid >> 6, l = tid & 63;
    const int q = l & 15, g4 = l >> 4;
    const int t0 = blockIdx.x * 16;

    const float* xr = x + (size_t)(t0 + q) * DIM;
    union { uint32_t u[4]; bf16x8 v; } a0, a1;
    #pragma unroll
    for (int j = 0; j < 4; ++j)
        a0.u[j] = pack2(xr[g4*8 + 2*j], xr[g4*8 + 2*j + 1]);
    a1.u[0] = 0; a1.u[1] = 0; a1.u[2] = 0; a1.u[3] = 0;
    if (g4 == 0) {
        a1.u[0] = pack2(xr[32], xr[33]);
        a1.u[1] = pack2(1.0f, 0.f);      // col 34 = bias slot
    }
    const f32x4 zero4 = {0.f, 0.f, 0.f, 0.f};

    f32x4 acc0 = zero4, acc1 = zero4, acc2 = zero4;
    for (int ph = 0; ph < 2; ++ph) {
        const int hb = wv*256 + ph*128;
        #pragma unroll
        for (int nt = 0; nt < 8; ++nt) {
            const u16* brow = W1b + (size_t)(hb + nt*16 + q) * 64 + g4*8;
            bf16x8 b0 = *(const bf16x8*)brow;
            bf16x8 b1f = *(const bf16x8*)(brow + 32);
            f32x4 c = MFMA16(a0.v, b0, zero4);
            c = MFMA16(a1.v, b1f, c);
            #pragma unroll
            for (int r = 0; r < 4; ++r) {
                int mm = 4*g4 + r;
                int byte = ((nt*16 + q) * 2) ^ ((mm & 7) << 4);
                *(u16*)((char*)&Hs[wv][mm][0] + byte) = f2bf(fmaxf(c[r], 0.f));
            }
        }
        __syncthreads();
        #pragma unroll
        for (int ks = 0; ks < 4; ++ks) {
            int byte = (ks*64 + g4*16) ^ ((q & 7) << 4);
            bf16x8 af = *(const bf16x8*)((char*)&Hs[wv][q][0] + byte);
            const u16* bp = W2b + (size_t)q * FFDIM + hb + ks*32 + g4*8;
            acc0 = MFMA16(af, *(const bf16x8*)bp, acc0);
            acc1 = MFMA16(af, *(const bf16x8*)(bp + 16*FFDIM), acc1);
            acc2 = MFMA16(af, *(const bf16x8*)(bp + 32*FFDIM), acc2);
        }
        __syncthreads();
    }
    #pragma unroll
    for (int r = 0; r < 4; ++r) {
        red[wv][4*g4 + r][q]      = acc0[r];
        red[wv][4*g4 + r][16 + q] = acc1[r];
        red[wv][4*g4 + r][32 + q] = acc2[r];
    }
    __syncthreads();
    for (int e = tid; e < 16*DIM; e += 512) {
        int tt = e / DIM, d = e % DIM;
        float v = x[(size_t)(t0 + tt)*DIM + d] + b2[d];
        #pragma unroll
        for (int w = 0; w < 8; ++w) v += red[w][tt][d];
        ys[tt][d] = v;
    }
    __syncthreads();
    if (tid < 16) {
        float s1 = 0.f, s2 = 0.f;
        #pragma unroll
        for (int d = 0; d < DIM; ++d) { float v = ys[tid][d]; s1 += v; s2 += v * v; }
        float mean = s1 * (1.0f / DIM);
        float var  = s2 * (1.0f / DIM) - mean * mean;
        stats[tid][0] = mean;
        stats[tid][1] = rsqrtf(var + 1e-5f);
    }
    __syncthreads();
    for (int e = tid; e < 16*DIM; e += 512) {
        int tt = e / DIM, d = e % DIM;
        float v = (ys[tt][d] - stats[tt][0]) * stats[tt][1] * g[d] + be[d];
        x[(size_t)(t0 + tt)*DIM + d] = v;
        ys[tt][d] = v;                   // final x tile kept in LDS for qkv
    }
    if (do_qkv) {
        __syncthreads();
        #pragma unroll
        for (int ii = 0; ii < 4; ++ii) {
            int e = tid + ii*512;
            if (e < 16*102) {
                int r = e >> 4, tt = e & 15;
                const float* wr = in_w + r*DIM;
                float a = in_b[r];
                #pragma unroll
                for (int d = 0; d < DIM; ++d) a = fmaf(ys[tt][d], wr[d], a);
                int tg = t0 + tt;
                if (r < 68) {
                    int rq = (r < 34) ? r : r - 34;
                    int h2 = rq >= HD, hs = rq - h2*HD;
                    u16 v = f2bf((r < 34) ? a*SC2 : a);
                    u16* dst = (r < 34) ? Qb : Kb;
                    dst[(((size_t)h2*SEQ + tg) << 5) + hs] = v;
                } else {
                    int rv = r - 68;
                    int h2 = rv >= HD, dd = rv - h2*HD;
                    u16 v = f2bf(a);
                    if (dd == 16) V16[h2*SEQ + tg] = v;
                    else {
                        int c = tg >> 5, gg = (tg >> 3) & 3, ix = tg & 7;
                        Vc[((((size_t)h2*128 + c)*4 + gg)*16 + dd)*8 + ix] = v;
                    }
                }
            }
        }
    }
}

// ---------------------------------------------------------------------------
// Kernel 4: final head (+ agent argmax + action embedding)
// ---------------------------------------------------------------------------
__global__ __launch_bounds__(64) void wm_final(const float* __restrict__ x,
        const float* __restrict__ obs, const int* __restrict__ action,
        const float* __restrict__ aw, const float* __restrict__ ab,
        const float* __restrict__ hw, const float* __restrict__ hb,
        float* __restrict__ out)
{
    __shared__ float hv[DIM];
    __shared__ float saemb[8];
    __shared__ int sai;
    const int tid = threadIdx.x;
    {
        float v = obs[tid];
        float mx = v;
        for (int off = 32; off; off >>= 1) mx = fmaxf(mx, __shfl_xor(mx, off));
        unsigned long long mask = __ballot(v == mx);
        if (tid == 0) sai = (int)(__ffsll(mask) - 1);
    }
    if (tid < 8) {
        int act = *action;
        saemb[tid] = fmaxf(aw[tid*4 + act] + ab[tid], 0.f);
    }
    __syncthreads();
    const int ai = sai;
    if (tid < DIM) {
        float s = 0.f;
        for (int r = 0; r < 64; ++r) s += x[(size_t)(ai*64 + r)*DIM + tid];
        hv[tid] = s * (1.0f / 64.0f);
    }
    __syncthreads();
    if (tid < 16) {
        float a = hb[tid];
        #pragma unroll
        for (int d = 0; d < DIM; ++d) a = fmaf(hv[d], hw[tid*42 + d], a);
        #pragma unroll
        for (int j = 0; j < 8; ++j) a = fmaf(saemb[j], hw[tid*42 + DIM + j], a);
        out[tid] = a;
    }
}

// ---------------------------------------------------------------------------
extern "C" void kernel_launch(void* const* d_in, const int* in_sizes, int n_in,
                              void* d_out, int out_size, void* d_ws, size_t ws_size,
                              hipStream_t stream)
{
    const float* obs    = (const float*)d_in[0];
    const int*   action = (const int*)  d_in[1];
    const float* c1w = (const float*)d_in[2];
    const float* c1b = (const float*)d_in[3];
    const float* c2w = (const float*)d_in[4];
    const float* c2b = (const float*)d_in[5];
    const float* aw  = (const float*)d_in[30];
    const float* ab  = (const float*)d_in[31];
    const float* hw  = (const float*)d_in[32];
    const float* hb  = (const float*)d_in[33];

    float* ws   = (float*)d_ws;
    float* x    = ws + 1056;                // 4096*34   (offsets kept from R5)
    float* o    = x + SEQ * DIM;            // (unused now)
    u16*   Qb   = (u16*)(o + SEQ * DIM);    // 2*4096*32 bf16
    u16*   Kb   = Qb + 2 * SEQ * 32;
    u16*   Vc   = Kb + 2 * SEQ * 32;        // 2*128*4*16*8 bf16
    u16*   V16  = Vc + 2 * 128 * 512;       // 2*4096 bf16
    u16*   W1b0 = V16 + 2 * SEQ;
    u16*   W2b0 = W1b0 + W1B_ELEMS;
    u16*   W1b1 = W2b0 + W2B_ELEMS;
    u16*   W2b1 = W1b1 + W1B_ELEMS;

    // 1: weight repack + conv/seq/qkv(l0)
    wm_pre<<<NWCONV + 64, 1024, 0, stream>>>(
        obs, c1w, c1b, c2w, c2b,
        (const float*)d_in[6], (const float*)d_in[7],
        (const float*)d_in[10], (const float*)d_in[11], (const float*)d_in[12],
        (const float*)d_in[22], (const float*)d_in[23], (const float*)d_in[24],
        x, Qb, Kb, Vc, V16, W1b0, W2b0, W1b1, W2b1);

    // 2: attn + projln (layer 0)
    wm_attn3<<<SEQ / 16, 512, 0, stream>>>(Qb, Kb, Vc, V16, x,
        (const float*)d_in[8], (const float*)d_in[9],
        (const float*)d_in[14], (const float*)d_in[15]);

    // 3: ffn + ln2 (layer 0) + qkv emit for layer 1
    wm_ff3<<<SEQ / 16, 512, 0, stream>>>(x, W1b0, W2b0,
        (const float*)d_in[13], (const float*)d_in[16], (const float*)d_in[17],
        (const float*)d_in[18], (const float*)d_in[19],
        Qb, Kb, Vc, V16, 1);

    // 4: attn + projln (layer 1)
    wm_attn3<<<SEQ / 16, 512, 0, stream>>>(Qb, Kb, Vc, V16, x,
        (const float*)d_in[20], (const float*)d_in[21],
        (const float*)d_in[26], (const float*)d_in[27]);

    // 5: ffn + ln2 (layer 1)
    wm_ff3<<<SEQ / 16, 512, 0, stream>>>(x, W1b1, W2b1,
        (const float*)d_in[25], (const float*)d_in[28], (const float*)d_in[29],
        (const float*)d_in[18], (const float*)d_in[19],
        Qb, Kb, Vc, V16, 0);

    // 6: final head
    wm_final<<<1, 64, 0, stream>>>(x, obs, action, aw, ab, hw, hb, (float*)d_out);
}

// Round 7
// 102.870 us; speedup vs baseline: 6.1305x; 1.2103x over previous
//
#include <hip/hip_runtime.h>
#include <math.h>

// Problem constants
#define SEQ 4096          // N*N tokens
#define DIM 34
#define NHEAD 2
#define HD 17
#define FFDIM 2048
// (1/sqrt(17)) * log2(e): fold softmax scale + exp2 conversion into Q
#define SC2 0.34990494f

#define EXP2F(x) __builtin_amdgcn_exp2f(x)
#define MFMA16(a, b, c) __builtin_amdgcn_mfma_f32_16x16x32_bf16(a, b, c, 0, 0, 0)

typedef unsigned short u16;
typedef __attribute__((ext_vector_type(8))) short bf16x8;
typedef __attribute__((ext_vector_type(4))) float f32x4;

__device__ inline u16 f2bf(float f) {
    uint32_t u = __builtin_bit_cast(uint32_t, f);
    u += 0x7fffu + ((u >> 16) & 1u);
    return (u16)(u >> 16);
}
__device__ inline uint32_t pack2(float a, float b) {
    uint32_t ua = __builtin_bit_cast(uint32_t, a);
    ua += 0x7fffu + ((ua >> 16) & 1u);
    uint32_t ub = __builtin_bit_cast(uint32_t, b);
    ub += 0x7fffu + ((ub >> 16) & 1u);
    return (ua >> 16) | (ub & 0xffff0000u);
}

#define W1B_ELEMS (FFDIM * 64)       // 131072
#define W2B_ELEMS (48 * FFDIM)       // 98304
#define NWCONV 448                   // 2*(W1B+W2B)/1024 blocks of repack work

// ---------------------------------------------------------------------------
// Kernel 1: wm_pre — block-partitioned:
//  blocks [0,448): repack FFN weights (both layers) to bf16 MFMA layouts
//  blocks [448,512): redundant conv1+conv2 in LDS, then emit x rows and
//                    layer-0 Q/K/V in MFMA-ready bf16 layouts (64 tokens/blk)
// ---------------------------------------------------------------------------
__global__ __launch_bounds__(1024) void wm_pre(
    const float* __restrict__ obs,
    const float* __restrict__ c1w, const float* __restrict__ c1b,
    const float* __restrict__ c2w, const float* __restrict__ c2b,
    const float* __restrict__ in_w, const float* __restrict__ in_b,   // layer 0
    const float* __restrict__ w1a, const float* __restrict__ b1a, const float* __restrict__ w2a,
    const float* __restrict__ w1b, const float* __restrict__ b1b, const float* __restrict__ w2b,
    float* __restrict__ x, u16* __restrict__ Qb, u16* __restrict__ Kb,
    u16* __restrict__ Vc, u16* __restrict__ V16,
    u16* __restrict__ W1A, u16* __restrict__ W2A,
    u16* __restrict__ W1B, u16* __restrict__ W2B)
{
    const int tid = threadIdx.x;
    if (blockIdx.x < NWCONV) {
        // ---- weight repack ----
        int id = blockIdx.x * 1024 + tid;
        const int half = W1B_ELEMS + W2B_ELEMS;
        const float* w1 = w1a; const float* b1 = b1a; const float* w2 = w2a;
        u16* W1 = W1A; u16* W2 = W2A;
        if (id >= half) { id -= half; w1 = w1b; b1 = b1b; w2 = w2b; W1 = W1B; W2 = W2B; }
        if (id < W1B_ELEMS) {
            int n = id >> 6, c = id & 63;
            float v = (c < DIM) ? w1[n*DIM + c] : ((c == DIM) ? b1[n] : 0.f);
            W1[id] = f2bf(v);
        } else {
            int e = id - W1B_ELEMS;
            int n = e >> 11;
            float v = (n < DIM) ? w2[(n << 11) + (e & 2047)] : 0.f;
            W2[e] = f2bf(v);
        }
        return;
    }
    // ---- conv + seq + qkv(layer 0) for 64 tokens ----
    __shared__ float obsp[2][10][10];
    __shared__ float h1p[16][10][10];
    __shared__ float cs[64][17];              // +1 pad: conflict-free cs[j][d]
    const int sb = blockIdx.x - NWCONV;       // 0..63
    const int t0 = sb * 64;

    for (int e = tid; e < 200; e += 1024) ((float*)obsp)[e] = 0.f;
    for (int e = tid; e < 1600; e += 1024) ((float*)h1p)[e] = 0.f;
    __syncthreads();
    if (tid < 128) {
        int i = tid >> 6, n = tid & 63, y = n >> 3, xx = n & 7;
        obsp[i][y + 1][xx + 1] = obs[tid];
    }
    __syncthreads();
    {   // conv1
        int o = tid >> 6, n = tid & 63, y = n >> 3, xx = n & 7;
        float a = c1b[o];
        #pragma unroll
        for (int i = 0; i < 2; ++i)
            #pragma unroll
            for (int ky = 0; ky < 3; ++ky)
                #pragma unroll
                for (int kx = 0; kx < 3; ++kx)
                    a = fmaf(obsp[i][y + ky][xx + kx], c1w[((o*2 + i)*3 + ky)*3 + kx], a);
        h1p[o][y + 1][xx + 1] = fmaxf(a, 0.f);
    }
    __syncthreads();
    {   // conv2 -> cs[n][o]
        int o = tid >> 6, n = tid & 63, y = n >> 3, xx = n & 7;
        float a = c2b[o];
        #pragma unroll
        for (int i = 0; i < 16; ++i)
            #pragma unroll
            for (int ky = 0; ky < 3; ++ky)
                #pragma unroll
                for (int kx = 0; kx < 3; ++kx)
                    a = fmaf(h1p[i][y + ky][xx + kx], c2w[((o*16 + i)*3 + ky)*3 + kx], a);
        cs[n][o] = fmaxf(a, 0.f);
    }
    __syncthreads();
    // emit x rows for tokens t0..t0+63
    for (int e = tid; e < 64 * DIM; e += 1024) {
        int tl = e / DIM, d = e % DIM;
        int t = t0 + tl, i = t >> 6, j = t & 63;
        float v;
        if (d < 16)       v = cs[i][d];
        else if (d < 32)  v = cs[j][d - 16];
        else if (d == 32) v = (float)((i >> 3) - (j >> 3)) * (1.0f / 3.5f);
        else              v = (float)((i & 7) - (j & 7)) * (1.0f / 3.5f);
        x[t0 * DIM + e] = v;
    }
    // emit layer-0 qkv: slot map identical to old wm_qkv2 (slot wave-uniform)
    for (int ii = 0; ii < 11; ++ii) {
        int e = tid + ii * 1024;
        if (e >= 64 * 162) break;
        int t = t0 + (e & 63), slot = e >> 6;
        int i = t >> 6, j = t & 63;
        float dx = (float)((i >> 3) - (j >> 3)) * (1.0f / 3.5f);
        float dy = (float)((i & 7) - (j & 7)) * (1.0f / 3.5f);
        if (slot < 128) {
            int isK = slot >> 6, h2 = (slot >> 5) & 1, hs = slot & 31;
            float val = 0.f;
            if (hs < HD) {
                int row = isK*DIM + h2*HD + hs;
                const float* wr = in_w + row*DIM;
                float a = in_b[row];
                #pragma unroll
                for (int d = 0; d < 16; ++d) a = fmaf(cs[i][d], wr[d], a);
                #pragma unroll
                for (int d = 0; d < 16; ++d) a = fmaf(cs[j][d], wr[16 + d], a);
                a = fmaf(dx, wr[32], a);
                a = fmaf(dy, wr[33], a);
                val = isK ? a : a * SC2;
            }
            u16* dst = isK ? Kb : Qb;
            dst[(((size_t)h2*SEQ + t) << 5) + hs] = f2bf(val);
        } else {
            int s = slot - 128;
            int h2 = s >= HD, dd = s - h2*HD;
            int row = 2*DIM + h2*HD + dd;
            const float* wr = in_w + row*DIM;
            float a = in_b[row];
            #pragma unroll
            for (int d = 0; d < 16; ++d) a = fmaf(cs[i][d], wr[d], a);
            #pragma unroll
            for (int d = 0; d < 16; ++d) a = fmaf(cs[j][d], wr[16 + d], a);
            a = fmaf(dx, wr[32], a);
            a = fmaf(dy, wr[33], a);
            u16 v = f2bf(a);
            if (dd == 16) V16[h2*SEQ + t] = v;
            else {
                int c = t >> 5, g = (t >> 3) & 3, ix = t & 7;
                Vc[((((size_t)h2*128 + c)*4 + g)*16 + dd)*8 + ix] = v;
            }
        }
    }
}

// ---------------------------------------------------------------------------
// Kernel 2: MFMA flash attention + out-proj + residual + LN1, in-place on x.
// 1024 thr = 16 waves: wave wv -> head wv>>3, key range (wv&7)*512..+512.
// Softmax batched over 64 keys (2 MFMA chunks) per iteration.
// ---------------------------------------------------------------------------
__global__ __launch_bounds__(1024) void wm_attn3(const u16* __restrict__ Qb,
        const u16* __restrict__ Kb, const u16* __restrict__ Vc,
        const u16* __restrict__ V16, float* __restrict__ x,
        const float* __restrict__ ow, const float* __restrict__ obias,
        const float* __restrict__ g, const float* __restrict__ be)
{
    const int qt = blockIdx.x;
    const int tid = threadIdx.x;
    const int wv = tid >> 6, l = tid & 63;
    const int h = wv >> 3, rr = wv & 7;
    const int q = l & 15, gg = l >> 4;

    __shared__ float red[16][64][9];
    __shared__ float os[16][DIM];
    __shared__ float ys[16][DIM];
    __shared__ float stats[16][2];

    const u16* Qh = Qb + (((size_t)h*SEQ + qt*16 + q) << 5) + 8*gg;
    const u16* Kh = Kb + ((size_t)h*SEQ << 5);
    const u16* Vh = Vc + (size_t)h*128*512;
    const u16* V6 = V16 + (size_t)h*SEQ;

    const bf16x8 qf = *(const bf16x8*)Qh;
    const f32x4 zero4 = {0.f, 0.f, 0.f, 0.f};

    f32x4 olo = zero4, ohi = zero4;
    float m = -INFINITY, lsum = 0.f;

    const int srcA = q + 32*(gg & 1);
    const int srcB = srcA + 16;
    const bool hi = (gg >= 2);

    for (int it = 0; it < 8; ++it) {
        const int cA = rr*16 + it*2;
        const int k0 = cA * 32;
        bf16x8 kf0 = *(const bf16x8*)(Kh + ((size_t)(k0 + q) << 5) + 8*gg);
        bf16x8 kf1 = *(const bf16x8*)(Kh + ((size_t)(k0 + 16 + q) << 5) + 8*gg);
        bf16x8 kf2 = *(const bf16x8*)(Kh + ((size_t)(k0 + 32 + q) << 5) + 8*gg);
        bf16x8 kf3 = *(const bf16x8*)(Kh + ((size_t)(k0 + 48 + q) << 5) + 8*gg);
        f32x4 s0 = MFMA16(kf0, qf, zero4);
        f32x4 s1 = MFMA16(kf1, qf, zero4);
        f32x4 s2 = MFMA16(kf2, qf, zero4);
        f32x4 s3 = MFMA16(kf3, qf, zero4);
        float tm = fmaxf(
            fmaxf(fmaxf(fmaxf(s0[0], s0[1]), fmaxf(s0[2], s0[3])),
                  fmaxf(fmaxf(s1[0], s1[1]), fmaxf(s1[2], s1[3]))),
            fmaxf(fmaxf(fmaxf(s2[0], s2[1]), fmaxf(s2[2], s2[3])),
                  fmaxf(fmaxf(s3[0], s3[1]), fmaxf(s3[2], s3[3]))));
        tm = fmaxf(tm, __shfl_xor(tm, 16));
        tm = fmaxf(tm, __shfl_xor(tm, 32));
        float newm = fmaxf(m, tm);
        float fac = EXP2F(m - newm);
        m = newm;
        float pa0 = EXP2F(s0[0] - m), pa1 = EXP2F(s0[1] - m);
        float pa2 = EXP2F(s0[2] - m), pa3 = EXP2F(s0[3] - m);
        float pa4 = EXP2F(s1[0] - m), pa5 = EXP2F(s1[1] - m);
        float pa6 = EXP2F(s1[2] - m), pa7 = EXP2F(s1[3] - m);
        float pb0 = EXP2F(s2[0] - m), pb1 = EXP2F(s2[1] - m);
        float pb2 = EXP2F(s2[2] - m), pb3 = EXP2F(s2[3] - m);
        float pb4 = EXP2F(s3[0] - m), pb5 = EXP2F(s3[1] - m);
        float pb6 = EXP2F(s3[2] - m), pb7 = EXP2F(s3[3] - m);
        float ts = (((pa0 + pa1) + (pa2 + pa3)) + ((pa4 + pa5) + (pa6 + pa7)))
                 + (((pb0 + pb1) + (pb2 + pb3)) + ((pb4 + pb5) + (pb6 + pb7)));
        ts += __shfl_xor(ts, 16);
        ts += __shfl_xor(ts, 32);
        lsum = lsum * fac + ts;
        olo[0] *= fac; olo[1] *= fac; olo[2] *= fac; olo[3] *= fac;
        ohi[0] *= fac; ohi[1] *= fac; ohi[2] *= fac; ohi[3] *= fac;
        // ---- chunk A redistribution + PV ----
        {
            uint32_t a0t0 = pack2(pa0, pa1), a1t0 = pack2(pa2, pa3);
            uint32_t a0t1 = pack2(pa4, pa5), a1t1 = pack2(pa6, pa7);
            uint32_t w0a = (uint32_t)__shfl((int)a0t0, srcA), w0b = (uint32_t)__shfl((int)a0t1, srcA);
            uint32_t w1a = (uint32_t)__shfl((int)a1t0, srcA), w1b = (uint32_t)__shfl((int)a1t1, srcA);
            uint32_t w2a = (uint32_t)__shfl((int)a0t0, srcB), w2b = (uint32_t)__shfl((int)a0t1, srcB);
            uint32_t w3a = (uint32_t)__shfl((int)a1t0, srcB), w3b = (uint32_t)__shfl((int)a1t1, srcB);
            union { uint32_t u[4]; bf16x8 v; } pu;
            pu.u[0] = hi ? w0b : w0a;
            pu.u[1] = hi ? w1b : w1a;
            pu.u[2] = hi ? w2b : w2a;
            pu.u[3] = hi ? w3b : w3a;
            bf16x8 vf = *(const bf16x8*)(Vh + (size_t)(cA*4 + gg)*128 + q*8);
            bf16x8 v6 = {};
            if (q == 0) v6 = *(const bf16x8*)(V6 + k0 + 8*gg);
            olo = MFMA16(vf, pu.v, olo);
            ohi = MFMA16(v6, pu.v, ohi);
        }
        // ---- chunk B redistribution + PV ----
        {
            uint32_t a0t0 = pack2(pb0, pb1), a1t0 = pack2(pb2, pb3);
            uint32_t a0t1 = pack2(pb4, pb5), a1t1 = pack2(pb6, pb7);
            uint32_t w0a = (uint32_t)__shfl((int)a0t0, srcA), w0b = (uint32_t)__shfl((int)a0t1, srcA);
            uint32_t w1a = (uint32_t)__shfl((int)a1t0, srcA), w1b = (uint32_t)__shfl((int)a1t1, srcA);
            uint32_t w2a = (uint32_t)__shfl((int)a0t0, srcB), w2b = (uint32_t)__shfl((int)a0t1, srcB);
            uint32_t w3a = (uint32_t)__shfl((int)a1t0, srcB), w3b = (uint32_t)__shfl((int)a1t1, srcB);
            union { uint32_t u[4]; bf16x8 v; } pu;
            pu.u[0] = hi ? w0b : w0a;
            pu.u[1] = hi ? w1b : w1a;
            pu.u[2] = hi ? w2b : w2a;
            pu.u[3] = hi ? w3b : w3a;
            bf16x8 vf = *(const bf16x8*)(Vh + (size_t)((cA + 1)*4 + gg)*128 + q*8);
            bf16x8 v6 = {};
            if (q == 0) v6 = *(const bf16x8*)(V6 + k0 + 32 + 8*gg);
            olo = MFMA16(vf, pu.v, olo);
            ohi = MFMA16(v6, pu.v, ohi);
        }
    }

    {
        float* r = red[wv][l];
        r[0] = m; r[1] = lsum;
        r[2] = olo[0]; r[3] = olo[1]; r[4] = olo[2]; r[5] = olo[3];
        r[6] = ohi[0];
    }
    __syncthreads();
    if (rr == 0) {
        float M = red[wv][l][0];
        #pragma unroll
        for (int p = 1; p < 8; ++p) M = fmaxf(M, red[wv + p][l][0]);
        float lt = 0.f, o0 = 0.f, o1 = 0.f, o2 = 0.f, o3 = 0.f, o6 = 0.f;
        #pragma unroll
        for (int p = 0; p < 8; ++p) {
            float* r = red[wv + p][l];
            float fp = EXP2F(r[0] - M);
            lt += r[1]*fp;
            o0 += r[2]*fp; o1 += r[3]*fp; o2 += r[4]*fp; o3 += r[5]*fp; o6 += r[6]*fp;
        }
        float inv = 1.f / lt;
        os[q][h*HD + 4*gg + 0] = o0*inv;
        os[q][h*HD + 4*gg + 1] = o1*inv;
        os[q][h*HD + 4*gg + 2] = o2*inv;
        os[q][h*HD + 4*gg + 3] = o3*inv;
        if (gg == 0) os[q][h*HD + 16] = o6*inv;
    }
    __syncthreads();
    // out-proj + residual
    for (int e = tid; e < 16 * DIM; e += 1024) {
        int tt = e / DIM, d = e % DIM;
        const float* wr = ow + d*DIM;
        float acc = obias[d];
        #pragma unroll
        for (int k = 0; k < DIM; ++k) acc = fmaf(os[tt][k], wr[k], acc);
        ys[tt][d] = x[(size_t)(qt*16 + tt)*DIM + d] + acc;
    }
    __syncthreads();
    if (tid < 16) {
        float s1 = 0.f, s2 = 0.f;
        #pragma unroll
        for (int d = 0; d < DIM; ++d) { float v = ys[tid][d]; s1 += v; s2 += v*v; }
        float mean = s1 * (1.0f / DIM);
        float var  = s2 * (1.0f / DIM) - mean*mean;
        stats[tid][0] = mean;
        stats[tid][1] = rsqrtf(var + 1e-5f);
    }
    __syncthreads();
    for (int e = tid; e < 16 * DIM; e += 1024) {
        int tt = e / DIM, d = e % DIM;
        x[(size_t)(qt*16 + tt)*DIM + d] = (ys[tt][d] - stats[tt][0]) * stats[tt][1] * g[d] + be[d];
    }
}

// ---------------------------------------------------------------------------
// Kernel 3: MFMA fused FFN + residual + LN2 (+ optional next-layer QKV emit).
// 1024 thr = 16 waves; wave wv owns hidden [wv*128, wv*128+128). Single
// phase: Hs is wave-private (no block barriers in the GEMM section).
// ---------------------------------------------------------------------------
__global__ __launch_bounds__(1024) void wm_ff3(float* __restrict__ x,
        const u16* __restrict__ W1b, const u16* __restrict__ W2b,
        const float* __restrict__ b2, const float* __restrict__ g,
        const float* __restrict__ be,
        const float* __restrict__ in_w, const float* __restrict__ in_b,
        u16* __restrict__ Qb, u16* __restrict__ Kb,
        u16* __restrict__ Vc, u16* __restrict__ V16, int do_qkv)
{
    __shared__ u16 Hs[16][16][128];      // 64 KB, wave-private, XOR-swizzled
    __shared__ float red[16][16][52];    // 53 KB
    __shared__ float ys[16][DIM];
    __shared__ float stats[16][2];
    const int tid = threadIdx.x, wv = tid >> 6, l = tid & 63;
    const int q = l & 15, g4 = l >> 4;
    const int t0 = blockIdx.x * 16;

    const float* xr = x + (size_t)(t0 + q) * DIM;
    union { uint32_t u[4]; bf16x8 v; } a0, a1;
    #pragma unroll
    for (int j = 0; j < 4; ++j)
        a0.u[j] = pack2(xr[g4*8 + 2*j], xr[g4*8 + 2*j + 1]);
    a1.u[0] = 0; a1.u[1] = 0; a1.u[2] = 0; a1.u[3] = 0;
    if (g4 == 0) {
        a1.u[0] = pack2(xr[32], xr[33]);
        a1.u[1] = pack2(1.0f, 0.f);      // col 34 = bias slot
    }
    const f32x4 zero4 = {0.f, 0.f, 0.f, 0.f};

    const int hb = wv * 128;
    // GEMM1: H[16 tokens][128 hidden] for this wave
    #pragma unroll
    for (int nt = 0; nt < 8; ++nt) {
        const u16* brow = W1b + (size_t)(hb + nt*16 + q) * 64 + g4*8;
        bf16x8 b0 = *(const bf16x8*)brow;
        bf16x8 b1f = *(const bf16x8*)(brow + 32);
        f32x4 c = MFMA16(a0.v, b0, zero4);
        c = MFMA16(a1.v, b1f, c);
        #pragma unroll
        for (int r = 0; r < 4; ++r) {
            int mm = 4*g4 + r;
            int byte = ((nt*16 + q) * 2) ^ ((mm & 7) << 4);
            *(u16*)((char*)&Hs[wv][mm][0] + byte) = f2bf(fmaxf(c[r], 0.f));
        }
    }
    // same-wave LDS RAW: drain writes before reads (wave-private buffer)
    asm volatile("s_waitcnt lgkmcnt(0)" ::: "memory");
    __builtin_amdgcn_sched_barrier(0);
    // GEMM2: K = this wave's 128 hidden
    f32x4 acc0 = zero4, acc1 = zero4, acc2 = zero4;
    #pragma unroll
    for (int ks = 0; ks < 4; ++ks) {
        int byte = (ks*64 + g4*16) ^ ((q & 7) << 4);
        bf16x8 af = *(const bf16x8*)((char*)&Hs[wv][q][0] + byte);
        const u16* bp = W2b + (size_t)q * FFDIM + hb + ks*32 + g4*8;
        acc0 = MFMA16(af, *(const bf16x8*)bp, acc0);
        acc1 = MFMA16(af, *(const bf16x8*)(bp + 16*FFDIM), acc1);
        acc2 = MFMA16(af, *(const bf16x8*)(bp + 32*FFDIM), acc2);
    }
    #pragma unroll
    for (int r = 0; r < 4; ++r) {
        red[wv][4*g4 + r][q]      = acc0[r];
        red[wv][4*g4 + r][16 + q] = acc1[r];
        red[wv][4*g4 + r][32 + q] = acc2[r];
    }
    __syncthreads();
    for (int e = tid; e < 16*DIM; e += 1024) {
        int tt = e / DIM, d = e % DIM;
        float v = x[(size_t)(t0 + tt)*DIM + d] + b2[d];
        #pragma unroll
        for (int w = 0; w < 16; ++w) v += red[w][tt][d];
        ys[tt][d] = v;
    }
    __syncthreads();
    if (tid < 16) {
        float s1 = 0.f, s2 = 0.f;
        #pragma unroll
        for (int d = 0; d < DIM; ++d) { float v = ys[tid][d]; s1 += v; s2 += v * v; }
        float mean = s1 * (1.0f / DIM);
        float var  = s2 * (1.0f / DIM) - mean * mean;
        stats[tid][0] = mean;
        stats[tid][1] = rsqrtf(var + 1e-5f);
    }
    __syncthreads();
    for (int e = tid; e < 16*DIM; e += 1024) {
        int tt = e / DIM, d = e % DIM;
        float v = (ys[tt][d] - stats[tt][0]) * stats[tt][1] * g[d] + be[d];
        x[(size_t)(t0 + tt)*DIM + d] = v;
        ys[tt][d] = v;                   // final x tile kept in LDS for qkv
    }
    if (do_qkv) {
        __syncthreads();
        #pragma unroll
        for (int ii = 0; ii < 2; ++ii) {
            int e = tid + ii*1024;
            if (e < 16*102) {
                int r = e >> 4, tt = e & 15;
                const float* wr = in_w + r*DIM;
                float a = in_b[r];
                #pragma unroll
                for (int d = 0; d < DIM; ++d) a = fmaf(ys[tt][d], wr[d], a);
                int tg = t0 + tt;
                if (r < 68) {
                    int rq = (r < 34) ? r : r - 34;
                    int h2 = rq >= HD, hs = rq - h2*HD;
                    u16 v = f2bf((r < 34) ? a*SC2 : a);
                    u16* dst = (r < 34) ? Qb : Kb;
                    dst[(((size_t)h2*SEQ + tg) << 5) + hs] = v;
                } else {
                    int rv = r - 68;
                    int h2 = rv >= HD, dd = rv - h2*HD;
                    u16 v = f2bf(a);
                    if (dd == 16) V16[h2*SEQ + tg] = v;
                    else {
                        int c = tg >> 5, gg = (tg >> 3) & 3, ix = tg & 7;
                        Vc[((((size_t)h2*128 + c)*4 + gg)*16 + dd)*8 + ix] = v;
                    }
                }
            }
        }
    }
}

// ---------------------------------------------------------------------------
// Kernel 4: final head (+ agent argmax + action embedding)
// ---------------------------------------------------------------------------
__global__ __launch_bounds__(64) void wm_final(const float* __restrict__ x,
        const float* __restrict__ obs, const int* __restrict__ action,
        const float* __restrict__ aw, const float* __restrict__ ab,
        const float* __restrict__ hw, const float* __restrict__ hb,
        float* __restrict__ out)
{
    __shared__ float hv[DIM];
    __shared__ float saemb[8];
    __shared__ int sai;
    const int tid = threadIdx.x;
    {
        float v = obs[tid];
        float mx = v;
        for (int off = 32; off; off >>= 1) mx = fmaxf(mx, __shfl_xor(mx, off));
        unsigned long long mask = __ballot(v == mx);
        if (tid == 0) sai = (int)(__ffsll(mask) - 1);
    }
    if (tid < 8) {
        int act = *action;
        saemb[tid] = fmaxf(aw[tid*4 + act] + ab[tid], 0.f);
    }
    __syncthreads();
    const int ai = sai;
    if (tid < DIM) {
        float s = 0.f;
        for (int r = 0; r < 64; ++r) s += x[(size_t)(ai*64 + r)*DIM + tid];
        hv[tid] = s * (1.0f / 64.0f);
    }
    __syncthreads();
    if (tid < 16) {
        float a = hb[tid];
        #pragma unroll
        for (int d = 0; d < DIM; ++d) a = fmaf(hv[d], hw[tid*42 + d], a);
        #pragma unroll
        for (int j = 0; j < 8; ++j) a = fmaf(saemb[j], hw[tid*42 + DIM + j], a);
        out[tid] = a;
    }
}

// ---------------------------------------------------------------------------
extern "C" void kernel_launch(void* const* d_in, const int* in_sizes, int n_in,
                              void* d_out, int out_size, void* d_ws, size_t ws_size,
                              hipStream_t stream)
{
    const float* obs    = (const float*)d_in[0];
    const int*   action = (const int*)  d_in[1];
    const float* c1w = (const float*)d_in[2];
    const float* c1b = (const float*)d_in[3];
    const float* c2w = (const float*)d_in[4];
    const float* c2b = (const float*)d_in[5];
    const float* aw  = (const float*)d_in[30];
    const float* ab  = (const float*)d_in[31];
    const float* hw  = (const float*)d_in[32];
    const float* hb  = (const float*)d_in[33];

    float* ws   = (float*)d_ws;
    float* x    = ws + 1056;                // 4096*34
    float* o    = x + SEQ * DIM;            // (unused)
    u16*   Qb   = (u16*)(o + SEQ * DIM);    // 2*4096*32 bf16
    u16*   Kb   = Qb + 2 * SEQ * 32;
    u16*   Vc   = Kb + 2 * SEQ * 32;        // 2*128*4*16*8 bf16
    u16*   V16  = Vc + 2 * 128 * 512;       // 2*4096 bf16
    u16*   W1b0 = V16 + 2 * SEQ;
    u16*   W2b0 = W1b0 + W1B_ELEMS;
    u16*   W1b1 = W2b0 + W2B_ELEMS;
    u16*   W2b1 = W1b1 + W1B_ELEMS;

    // 1: weight repack + conv/seq/qkv(l0)
    wm_pre<<<NWCONV + 64, 1024, 0, stream>>>(
        obs, c1w, c1b, c2w, c2b,
        (const float*)d_in[6], (const float*)d_in[7],
        (const float*)d_in[10], (const float*)d_in[11], (const float*)d_in[12],
        (const float*)d_in[22], (const float*)d_in[23], (const float*)d_in[24],
        x, Qb, Kb, Vc, V16, W1b0, W2b0, W1b1, W2b1);

    // 2: attn + projln (layer 0)
    wm_attn3<<<SEQ / 16, 1024, 0, stream>>>(Qb, Kb, Vc, V16, x,
        (const float*)d_in[8], (const float*)d_in[9],
        (const float*)d_in[14], (const float*)d_in[15]);

    // 3: ffn + ln2 (layer 0) + qkv emit for layer 1
    wm_ff3<<<SEQ / 16, 1024, 0, stream>>>(x, W1b0, W2b0,
        (const float*)d_in[13], (const float*)d_in[16], (const float*)d_in[17],
        (const float*)d_in[18], (const float*)d_in[19],
        Qb, Kb, Vc, V16, 1);

    // 4: attn + projln (layer 1)
    wm_attn3<<<SEQ / 16, 1024, 0, stream>>>(Qb, Kb, Vc, V16, x,
        (const float*)d_in[20], (const float*)d_in[21],
        (const float*)d_in[26], (const float*)d_in[27]);

    // 5: ffn + ln2 (layer 1)
    wm_ff3<<<SEQ / 16, 1024, 0, stream>>>(x, W1b1, W2b1,
        (const float*)d_in[25], (const float*)d_in[28], (const float*)d_in[29],
        (const float*)d_in[18], (const float*)d_in[19],
        Qb, Kb, Vc, V16, 0);

    // 6: final head
    wm_final<<<1, 64, 0, stream>>>(x, obs, action, aw, ab, hw, hb, (float*)d_out);
}